// Round 1
// baseline (877.538 us; speedup 1.0000x reference)
//
#include <hip/hip_runtime.h>
#include <math.h>

#define D 256
#define NH 8
#define NL 4
#define NP 4
#define DFF 2048
#define HD 32
#define BB 2
#define LEN 5440
#define MROWS (BB * LEN)   // 10880

// ---------------------------------------------------------------------------
// Generic GEMM: C[M x N] = (A [+ P]) @ W[K=256 x N] + bias, N <= 256.
// 4 rows per block, blockDim.x == N. A rows staged in LDS (broadcast reads).
// ---------------------------------------------------------------------------
__global__ void gemm_k256(const float* __restrict__ A, const float* __restrict__ P,
                          const float* __restrict__ W, const float* __restrict__ bias,
                          float* __restrict__ C, int N) {
    __shared__ __align__(16) float ash[4][D];
    const int t = threadIdx.x;
    const int row0 = blockIdx.x * 4;

    for (int idx = t; idx < 4 * D; idx += blockDim.x) {
        int r = idx >> 8, k = idx & 255;
        float v = A[(size_t)(row0 + r) * D + k];
        if (P) v += P[(size_t)(row0 + r) * D + k];
        ash[r][k] = v;
    }
    __syncthreads();

    float b = bias[t];
    float acc0 = b, acc1 = b, acc2 = b, acc3 = b;
    const float* wp = W + t;
    for (int k = 0; k < D; k += 4) {
        float4 a0 = *(const float4*)&ash[0][k];
        float4 a1 = *(const float4*)&ash[1][k];
        float4 a2 = *(const float4*)&ash[2][k];
        float4 a3 = *(const float4*)&ash[3][k];
        float w0 = wp[(k + 0) * N];
        float w1 = wp[(k + 1) * N];
        float w2 = wp[(k + 2) * N];
        float w3 = wp[(k + 3) * N];
        acc0 += a0.x * w0 + a0.y * w1 + a0.z * w2 + a0.w * w3;
        acc1 += a1.x * w0 + a1.y * w1 + a1.z * w2 + a1.w * w3;
        acc2 += a2.x * w0 + a2.y * w1 + a2.z * w2 + a2.w * w3;
        acc3 += a3.x * w0 + a3.y * w1 + a3.z * w2 + a3.w * w3;
    }
    C[(size_t)(row0 + 0) * N + t] = acc0;
    C[(size_t)(row0 + 1) * N + t] = acc1;
    C[(size_t)(row0 + 2) * N + t] = acc2;
    C[(size_t)(row0 + 3) * N + t] = acc3;
}

// ---------------------------------------------------------------------------
// Deformable-attention sampler + softmax + attn-weighted sum.
// One block per (b,q); thread t -> head h = t>>5, dim d = t&31.
// value layout: (B, LEN, NH, HD); off: (B,LEN, NH*NL*NP*2); logits: (B,LEN,128)
// out: (B, LEN, D) with D index = h*32+d
// ---------------------------------------------------------------------------
__global__ void sampler(const float* __restrict__ val, const float* __restrict__ off,
                        const float* __restrict__ logits, float* __restrict__ out) {
    const int bq = blockIdx.x;
    const int b = bq / LEN, q = bq % LEN;
    const int t = threadIdx.x;
    const int h = t >> 5, d = t & 31;

    // reference point for this query (depends on its own level)
    float refx, refy;
    if (q < 4096) {
        int rq = q >> 6, cq = q & 63;
        refx = (cq + 0.5f) * (1.0f / 64.0f);
        refy = (rq + 0.5f) * (1.0f / 64.0f);
    } else if (q < 5120) {
        int qq = q - 4096;
        int rq = qq >> 5, cq = qq & 31;
        refx = (cq + 0.5f) * (1.0f / 32.0f);
        refy = (rq + 0.5f) * (1.0f / 32.0f);
    } else if (q < 5376) {
        int qq = q - 5120;
        int rq = qq >> 4, cq = qq & 15;
        refx = (cq + 0.5f) * (1.0f / 16.0f);
        refy = (rq + 0.5f) * (1.0f / 16.0f);
    } else {
        int qq = q - 5376;
        int rq = qq >> 3, cq = qq & 7;
        refx = (cq + 0.5f) * (1.0f / 8.0f);
        refy = (rq + 0.5f) * (1.0f / 8.0f);
    }

    // softmax over the head's 16 attention logits (redundant across 32 dims)
    const float* lg = logits + (size_t)bq * 128 + h * 16;
    float lv[16];
    float mx = -1e30f;
#pragma unroll
    for (int i = 0; i < 16; i++) { lv[i] = lg[i]; mx = fmaxf(mx, lv[i]); }
    float s = 0.f;
#pragma unroll
    for (int i = 0; i < 16; i++) { lv[i] = expf(lv[i] - mx); s += lv[i]; }
    const float inv = 1.0f / s;

    const float* op = off + (size_t)bq * D + h * (NL * NP * 2);

    const int LST[4] = {0, 4096, 5120, 5376};
    const int LW[4]  = {64, 32, 16, 8};
    const float LRW[4] = {1.0f / 64.0f, 1.0f / 32.0f, 1.0f / 16.0f, 1.0f / 8.0f};

    float acc = 0.f;
#pragma unroll
    for (int l = 0; l < 4; l++) {
        const int WW = LW[l];
        const int HH = WW;
        const float rw = LRW[l];
        const float* vbase = val + ((size_t)b * LEN + LST[l]) * D + h * HD + d;
#pragma unroll
        for (int p = 0; p < 4; p++) {
            float ox = op[(l * 4 + p) * 2 + 0];
            float oy = op[(l * 4 + p) * 2 + 1];
            // match reference arithmetic: loc = ref + off/W; x = loc*W - 0.5
            float locx = refx + ox * rw;
            float locy = refy + oy * rw;
            float x = locx * (float)WW - 0.5f;
            float y = locy * (float)HH - 0.5f;
            float x0f = floorf(x), y0f = floorf(y);
            float dx = x - x0f, dy = y - y0f;
            int x0 = (int)x0f, y0 = (int)y0f;
            float aw = lv[l * 4 + p] * inv;

            float cw[4] = {(1.f - dx) * (1.f - dy), dx * (1.f - dy),
                           (1.f - dx) * dy, dx * dy};
            int xs[4] = {x0, x0 + 1, x0, x0 + 1};
            int ys[4] = {y0, y0, y0 + 1, y0 + 1};
#pragma unroll
            for (int c = 0; c < 4; c++) {
                int xi = xs[c], yi = ys[c];
                bool vld = (xi >= 0) && (xi < WW) && (yi >= 0) && (yi < HH);
                int xc = min(max(xi, 0), WW - 1);
                int yc = min(max(yi, 0), HH - 1);
                float g = vbase[(size_t)(yc * WW + xc) * D];
                acc += g * (vld ? cw[c] * aw : 0.f);
            }
        }
    }
    out[(size_t)bq * D + h * HD + d] = acc;
}

// ---------------------------------------------------------------------------
// out-proj + residual + LayerNorm 1. One block (256 thr) per row.
// ---------------------------------------------------------------------------
__global__ void outproj_ln(const float* __restrict__ ao, const float* __restrict__ src,
                           const float* __restrict__ Wo, const float* __restrict__ bo,
                           const float* __restrict__ g1, const float* __restrict__ be1,
                           float* __restrict__ xout) {
    __shared__ __align__(16) float sh[D];
    __shared__ float r1[4], r2[4];
    const int bq = blockIdx.x, t = threadIdx.x;

    sh[t] = ao[(size_t)bq * D + t];
    __syncthreads();

    float acc = bo[t];
    const float* wp = Wo + t;
    for (int k = 0; k < D; k += 4) {
        float4 a = *(const float4*)&sh[k];
        acc += a.x * wp[(k + 0) * D] + a.y * wp[(k + 1) * D] +
               a.z * wp[(k + 2) * D] + a.w * wp[(k + 3) * D];
    }
    float v = acc + src[(size_t)bq * D + t];

    float s1 = v, s2 = v * v;
#pragma unroll
    for (int o = 32; o > 0; o >>= 1) {
        s1 += __shfl_down(s1, o, 64);
        s2 += __shfl_down(s2, o, 64);
    }
    const int w = t >> 6, lane = t & 63;
    if (lane == 0) { r1[w] = s1; r2[w] = s2; }
    __syncthreads();
    float su = r1[0] + r1[1] + r1[2] + r1[3];
    float sq = r2[0] + r2[1] + r2[2] + r2[3];
    float mean = su * (1.0f / D);
    float var = fmaxf(sq * (1.0f / D) - mean * mean, 0.f);
    float xn = (v - mean) * rsqrtf(var + 1e-5f);
    xout[(size_t)bq * D + t] = xn * g1[t] + be1[t];
}

// ---------------------------------------------------------------------------
// Fused FFN + residual + LayerNorm 2. 4 rows per block, hidden kept in LDS.
// ---------------------------------------------------------------------------
__global__ void ffn_ln(const float* __restrict__ x, const float* __restrict__ W1,
                       const float* __restrict__ b1, const float* __restrict__ W2,
                       const float* __restrict__ b2, const float* __restrict__ g2,
                       const float* __restrict__ be2, float* __restrict__ out) {
    __shared__ __align__(16) float xsh[4][D];
    __shared__ __align__(16) float hsh[4][DFF];
    __shared__ float red[4][8];
    const int t = threadIdx.x;
    const int row0 = blockIdx.x * 4;

    for (int idx = t; idx < 4 * D; idx += 256) {
        int r = idx >> 8, k = idx & 255;
        xsh[r][k] = x[(size_t)(row0 + r) * D + k];
    }
    __syncthreads();

    // ---- phase B: hidden = relu(x @ W1 + b1), 8 cols per thread ----
    float acc[4][8];
#pragma unroll
    for (int i = 0; i < 8; i++) {
        float bv = b1[i * 256 + t];
#pragma unroll
        for (int r = 0; r < 4; r++) acc[r][i] = bv;
    }
    for (int k = 0; k < D; k++) {
        float a0 = xsh[0][k], a1 = xsh[1][k], a2 = xsh[2][k], a3 = xsh[3][k];
        const float* wp = W1 + (size_t)k * DFF + t;
#pragma unroll
        for (int i = 0; i < 8; i++) {
            float wv = wp[i * 256];
            acc[0][i] += a0 * wv;
            acc[1][i] += a1 * wv;
            acc[2][i] += a2 * wv;
            acc[3][i] += a3 * wv;
        }
    }
#pragma unroll
    for (int i = 0; i < 8; i++)
#pragma unroll
        for (int r = 0; r < 4; r++) hsh[r][i * 256 + t] = fmaxf(acc[r][i], 0.f);
    __syncthreads();

    // ---- phase C: out = hidden @ W2 + b2 ----
    float bv2 = b2[t];
    float o0 = bv2, o1 = bv2, o2 = bv2, o3 = bv2;
    const float* wp2 = W2 + t;
    for (int k = 0; k < DFF; k += 4) {
        float4 h0 = *(const float4*)&hsh[0][k];
        float4 h1 = *(const float4*)&hsh[1][k];
        float4 h2 = *(const float4*)&hsh[2][k];
        float4 h3 = *(const float4*)&hsh[3][k];
        float w0 = wp2[(k + 0) * D];
        float w1 = wp2[(k + 1) * D];
        float w2 = wp2[(k + 2) * D];
        float w3 = wp2[(k + 3) * D];
        o0 += h0.x * w0 + h0.y * w1 + h0.z * w2 + h0.w * w3;
        o1 += h1.x * w0 + h1.y * w1 + h1.z * w2 + h1.w * w3;
        o2 += h2.x * w0 + h2.y * w1 + h2.z * w2 + h2.w * w3;
        o3 += h3.x * w0 + h3.y * w1 + h3.z * w2 + h3.w * w3;
    }

    // ---- residual + LN per row ----
    float vr[4];
    vr[0] = o0 + xsh[0][t];
    vr[1] = o1 + xsh[1][t];
    vr[2] = o2 + xsh[2][t];
    vr[3] = o3 + xsh[3][t];

    float s1[4], s2[4];
#pragma unroll
    for (int r = 0; r < 4; r++) { s1[r] = vr[r]; s2[r] = vr[r] * vr[r]; }
#pragma unroll
    for (int o = 32; o > 0; o >>= 1) {
#pragma unroll
        for (int r = 0; r < 4; r++) {
            s1[r] += __shfl_down(s1[r], o, 64);
            s2[r] += __shfl_down(s2[r], o, 64);
        }
    }
    const int w = t >> 6, lane = t & 63;
    if (lane == 0) {
#pragma unroll
        for (int r = 0; r < 4; r++) { red[w][r] = s1[r]; red[w][4 + r] = s2[r]; }
    }
    __syncthreads();
#pragma unroll
    for (int r = 0; r < 4; r++) {
        float su = red[0][r] + red[1][r] + red[2][r] + red[3][r];
        float sq = red[0][4 + r] + red[1][4 + r] + red[2][4 + r] + red[3][4 + r];
        float mean = su * (1.0f / D);
        float var = fmaxf(sq * (1.0f / D) - mean * mean, 0.f);
        float xn = (vr[r] - mean) * rsqrtf(var + 1e-5f);
        out[(size_t)(row0 + r) * D + t] = xn * g2[t] + be2[t];
    }
}

// ---------------------------------------------------------------------------
extern "C" void kernel_launch(void* const* d_in, const int* in_sizes, int n_in,
                              void* d_out, int out_size, void* d_ws, size_t ws_size,
                              hipStream_t stream) {
    const float* src     = (const float*)d_in[0];
    const float* pos     = (const float*)d_in[1];
    // d_in[2] spatial_shapes (int), d_in[3] level_start_index (int): constants, hardcoded
    const float* w_value = (const float*)d_in[4];
    const float* b_value = (const float*)d_in[5];
    const float* w_off   = (const float*)d_in[6];
    const float* b_off   = (const float*)d_in[7];
    const float* w_attn  = (const float*)d_in[8];
    const float* b_attn  = (const float*)d_in[9];
    const float* w_out   = (const float*)d_in[10];
    const float* b_out   = (const float*)d_in[11];
    const float* w1      = (const float*)d_in[12];
    const float* b1      = (const float*)d_in[13];
    const float* w2      = (const float*)d_in[14];
    const float* b2      = (const float*)d_in[15];
    const float* g1      = (const float*)d_in[16];
    const float* be1     = (const float*)d_in[17];
    const float* g2      = (const float*)d_in[18];
    const float* be2     = (const float*)d_in[19];
    float* out = (float*)d_out;

    float* ws       = (float*)d_ws;
    float* val      = ws;                                  // M*256
    float* offb     = val + (size_t)MROWS * 256;           // M*256
    float* logits   = offb + (size_t)MROWS * 256;          // M*128
    float* attn_out = logits + (size_t)MROWS * 128;        // M*256
    float* xbuf     = attn_out + (size_t)MROWS * 256;      // M*256

    gemm_k256<<<MROWS / 4, 256, 0, stream>>>(src, nullptr, w_value, b_value, val, 256);
    gemm_k256<<<MROWS / 4, 256, 0, stream>>>(src, pos, w_off, b_off, offb, 256);
    gemm_k256<<<MROWS / 4, 128, 0, stream>>>(src, pos, w_attn, b_attn, logits, 128);
    sampler<<<MROWS, 256, 0, stream>>>(val, offb, logits, attn_out);
    outproj_ln<<<MROWS, 256, 0, stream>>>(attn_out, src, w_out, b_out, g1, be1, xbuf);
    ffn_ln<<<MROWS / 4, 256, 0, stream>>>(xbuf, w1, b1, w2, b2, g2, be2, out);
}

// Round 4
// 361.627 us; speedup vs baseline: 2.4266x; 2.4266x over previous
//
#include <hip/hip_runtime.h>
#include <math.h>

#define D 256
#define NH 8
#define NL 4
#define NP 4
#define DFF 2048
#define HD 32
#define BB 2
#define LEN 5440
#define MROWS (BB * LEN)   // 10880 = 85 * 128 exactly

typedef __attribute__((ext_vector_type(8))) short short8;
typedef __attribute__((ext_vector_type(4))) float f32x4;
typedef unsigned int uint32;

__device__ __forceinline__ unsigned short f2bf(float f) {
    uint32 u = __float_as_uint(f);
    u += 0x7FFF + ((u >> 16) & 1);           // round-to-nearest-even
    return (unsigned short)(u >> 16);
}
__device__ __forceinline__ float bf2f(unsigned short h) {
    return __uint_as_float(((uint32)h) << 16);
}
__device__ __forceinline__ uint32 pack2(float a, float b) {
    return (uint32)f2bf(a) | ((uint32)f2bf(b) << 16);
}

// ---------------------------------------------------------------------------
// Transpose fp32 W[K x N] -> bf16 WT[N x K] (row stride K). 32x32 LDS tiles.
// grid: (N/32, K/32), block: 256 (= 32x8)
// ---------------------------------------------------------------------------
__global__ void transpose_bf16(const float* __restrict__ W, unsigned short* __restrict__ WT,
                               int K, int N) {
    __shared__ float tile[32][33];
    const int nb = blockIdx.x * 32, kb = blockIdx.y * 32;
    const int tx = threadIdx.x & 31, ty = threadIdx.x >> 5;   // ty 0..7
#pragma unroll
    for (int i = 0; i < 32; i += 8)
        tile[ty + i][tx] = W[(size_t)(kb + ty + i) * N + nb + tx];
    __syncthreads();
#pragma unroll
    for (int i = 0; i < 32; i += 8)
        WT[(size_t)(nb + ty + i) * K + kb + tx] = f2bf(tile[tx][ty + i]);
}

// concat b_off(256) ++ b_attn(128) -> bq(384)
__global__ void concat_bias(const float* __restrict__ b_off, const float* __restrict__ b_attn,
                            float* __restrict__ bq) {
    int t = threadIdx.x;
    if (t < 256) bq[t] = b_off[t];
    else if (t < 384) bq[t] = b_attn[t - 256];
}

// ---------------------------------------------------------------------------
// Generic bf16 MFMA GEMM: C[M x N] = A[M x K] @ BT[N x K]^T + bias (or +C)
//   A: bf16 (A_FP32=false, row stride lda) or fp32 (+ optional P) converted
//   BT: bf16, N x K row-major with row stride ldb (pre-transposed weight)
//   tile 128x128, block 256 thr = 4 waves (2x2 of 64x64), BK=32
//   Staging: each thread fills 16 shorts (= 32 bytes) of one LDS row half.
//   (Round-2/3 bug: bf16 paths copied only 8 shorts -> uninitialized LDS
//    in k in [8,16)u[24,32) fragments -> NaN. Fixed: two uint4 copies.)
//   MFMA 16x16x32_bf16: A[m=lane&15][k=quad*8+j], B[n=lane&15][k=quad*8+j],
//   C/D col=lane&15 row=quad*4+reg  [verified layouts]
//   ACCUM: C += A@B (bias ignored); else C = A@B + bias
// ---------------------------------------------------------------------------
template <bool A_FP32, bool ADD_P, bool RELU, bool OUT_BF16, bool ACCUM>
__global__ __launch_bounds__(256) void mfma_gemm(
        const void* __restrict__ Av, const float* __restrict__ P,
        const unsigned short* __restrict__ BT, const float* __restrict__ bias,
        void* __restrict__ Cv, int N, int K, int lda, int ldb) {
    __shared__ unsigned short Ash[128][40];   // +8 pad
    __shared__ unsigned short Bsh[128][40];

    const int t = threadIdx.x;
    const int wave = t >> 6, lane = t & 63;
    const int wr = wave >> 1, wc = wave & 1;
    const int lrow = lane & 15, quad = lane >> 4;
    const int row0 = blockIdx.x * 128;
    const int col0 = blockIdx.y * 128;

    const int srow = t >> 1;
    const int cb = (t & 1) * 16;

    f32x4 acc[4][4];
#pragma unroll
    for (int i = 0; i < 4; i++)
#pragma unroll
        for (int j = 0; j < 4; j++) acc[i][j] = (f32x4){0.f, 0.f, 0.f, 0.f};

    for (int kb = 0; kb < K; kb += 32) {
        __syncthreads();
        // ---- stage A: 16 elements (32 bytes) per thread ----
        if (A_FP32) {
            const float* ap = (const float*)Av + (size_t)(row0 + srow) * lda + kb + cb;
            float4 f0 = *(const float4*)(ap + 0);
            float4 f1 = *(const float4*)(ap + 4);
            float4 f2 = *(const float4*)(ap + 8);
            float4 f3 = *(const float4*)(ap + 12);
            if (ADD_P) {
                const float* pp = P + (size_t)(row0 + srow) * lda + kb + cb;
                float4 p0 = *(const float4*)(pp + 0);
                float4 p1 = *(const float4*)(pp + 4);
                float4 p2 = *(const float4*)(pp + 8);
                float4 p3 = *(const float4*)(pp + 12);
                f0.x += p0.x; f0.y += p0.y; f0.z += p0.z; f0.w += p0.w;
                f1.x += p1.x; f1.y += p1.y; f1.z += p1.z; f1.w += p1.w;
                f2.x += p2.x; f2.y += p2.y; f2.z += p2.z; f2.w += p2.w;
                f3.x += p3.x; f3.y += p3.y; f3.z += p3.z; f3.w += p3.w;
            }
            uint4 u0 = make_uint4(pack2(f0.x, f0.y), pack2(f0.z, f0.w),
                                  pack2(f1.x, f1.y), pack2(f1.z, f1.w));
            uint4 u1 = make_uint4(pack2(f2.x, f2.y), pack2(f2.z, f2.w),
                                  pack2(f3.x, f3.y), pack2(f3.z, f3.w));
            *(uint4*)&Ash[srow][cb + 0] = u0;
            *(uint4*)&Ash[srow][cb + 8] = u1;
        } else {
            const unsigned short* ap = (const unsigned short*)Av + (size_t)(row0 + srow) * lda + kb + cb;
            *(uint4*)&Ash[srow][cb + 0] = *(const uint4*)(ap + 0);
            *(uint4*)&Ash[srow][cb + 8] = *(const uint4*)(ap + 8);
        }
        // ---- stage B: 16 elements (32 bytes) per thread ----
        {
            const unsigned short* bp = BT + (size_t)(col0 + srow) * ldb + kb + cb;
            *(uint4*)&Bsh[srow][cb + 0] = *(const uint4*)(bp + 0);
            *(uint4*)&Bsh[srow][cb + 8] = *(const uint4*)(bp + 8);
        }
        __syncthreads();

        short8 af[4], bfr[4];
#pragma unroll
        for (int mt = 0; mt < 4; mt++)
            af[mt] = *(const short8*)&Ash[wr * 64 + mt * 16 + lrow][quad * 8];
#pragma unroll
        for (int nt = 0; nt < 4; nt++)
            bfr[nt] = *(const short8*)&Bsh[wc * 64 + nt * 16 + lrow][quad * 8];
#pragma unroll
        for (int mt = 0; mt < 4; mt++)
#pragma unroll
            for (int nt = 0; nt < 4; nt++)
                acc[mt][nt] = __builtin_amdgcn_mfma_f32_16x16x32_bf16(
                    af[mt], bfr[nt], acc[mt][nt], 0, 0, 0);
    }

    // ---- epilogue ----
#pragma unroll
    for (int nt = 0; nt < 4; nt++) {
        const int col = col0 + wc * 64 + nt * 16 + lrow;
        const float bv = ACCUM ? 0.f : bias[col];
#pragma unroll
        for (int mt = 0; mt < 4; mt++) {
            f32x4 a = acc[mt][nt];
#pragma unroll
            for (int r = 0; r < 4; r++) {
                const int row = row0 + wr * 64 + mt * 16 + quad * 4 + r;
                float v = a[r] + bv;
                if (ACCUM) v += ((const float*)Cv)[(size_t)row * N + col];
                if (RELU) v = fmaxf(v, 0.f);
                if (OUT_BF16)
                    ((unsigned short*)Cv)[(size_t)row * N + col] = f2bf(v);
                else
                    ((float*)Cv)[(size_t)row * N + col] = v;
            }
        }
    }
}

// ---------------------------------------------------------------------------
// Sampler: softmax over 16 logits + bilinear gather + weighted sum.
// qout: M x 384 fp32 (cols 0..255 = offsets, 256..383 = logits)
// val: M x 256 bf16; out: M x 256 bf16
// ---------------------------------------------------------------------------
__global__ void sampler(const unsigned short* __restrict__ val, const float* __restrict__ qout,
                        unsigned short* __restrict__ out) {
    const int bq = blockIdx.x;
    const int b = bq / LEN, q = bq % LEN;
    const int t = threadIdx.x;
    const int h = t >> 5, d = t & 31;

    float refx, refy;
    if (q < 4096) {
        int rq = q >> 6, cq = q & 63;
        refx = (cq + 0.5f) * (1.0f / 64.0f);
        refy = (rq + 0.5f) * (1.0f / 64.0f);
    } else if (q < 5120) {
        int qq = q - 4096;
        int rq = qq >> 5, cq = qq & 31;
        refx = (cq + 0.5f) * (1.0f / 32.0f);
        refy = (rq + 0.5f) * (1.0f / 32.0f);
    } else if (q < 5376) {
        int qq = q - 5120;
        int rq = qq >> 4, cq = qq & 15;
        refx = (cq + 0.5f) * (1.0f / 16.0f);
        refy = (rq + 0.5f) * (1.0f / 16.0f);
    } else {
        int qq = q - 5376;
        int rq = qq >> 3, cq = qq & 7;
        refx = (cq + 0.5f) * (1.0f / 8.0f);
        refy = (rq + 0.5f) * (1.0f / 8.0f);
    }

    const float* lg = qout + (size_t)bq * 384 + 256 + h * 16;
    float lv[16];
    float mx = -1e30f;
#pragma unroll
    for (int i = 0; i < 16; i++) { lv[i] = lg[i]; mx = fmaxf(mx, lv[i]); }
    float s = 0.f;
#pragma unroll
    for (int i = 0; i < 16; i++) { lv[i] = expf(lv[i] - mx); s += lv[i]; }
    const float inv = 1.0f / s;

    const float* op = qout + (size_t)bq * 384 + h * 32;

    const int LST[4] = {0, 4096, 5120, 5376};
    const int LW[4]  = {64, 32, 16, 8};
    const float LRW[4] = {1.0f / 64.0f, 1.0f / 32.0f, 1.0f / 16.0f, 1.0f / 8.0f};

    float acc = 0.f;
#pragma unroll
    for (int l = 0; l < 4; l++) {
        const int WW = LW[l];
        const float rw = LRW[l];
        const unsigned short* vbase = val + ((size_t)b * LEN + LST[l]) * D + h * HD + d;
#pragma unroll
        for (int p = 0; p < 4; p++) {
            float ox = op[(l * 4 + p) * 2 + 0];
            float oy = op[(l * 4 + p) * 2 + 1];
            float x = (refx + ox * rw) * (float)WW - 0.5f;
            float y = (refy + oy * rw) * (float)WW - 0.5f;
            float x0f = floorf(x), y0f = floorf(y);
            float dx = x - x0f, dy = y - y0f;
            int x0 = (int)x0f, y0 = (int)y0f;
            float aw = lv[l * 4 + p] * inv;

            float cw[4] = {(1.f - dx) * (1.f - dy), dx * (1.f - dy),
                           (1.f - dx) * dy, dx * dy};
            int xs[4] = {x0, x0 + 1, x0, x0 + 1};
            int ys[4] = {y0, y0, y0 + 1, y0 + 1};
#pragma unroll
            for (int c = 0; c < 4; c++) {
                int xi = xs[c], yi = ys[c];
                bool vld = (xi >= 0) && (xi < WW) && (yi >= 0) && (yi < WW);
                int xc = min(max(xi, 0), WW - 1);
                int yc = min(max(yi, 0), WW - 1);
                float g = bf2f(vbase[(size_t)(yc * WW + xc) * D]);
                acc += g * (vld ? cw[c] * aw : 0.f);
            }
        }
    }
    out[(size_t)bq * D + h * HD + d] = f2bf(acc);
}

// ---------------------------------------------------------------------------
// out = LayerNorm(a + rsd) * g + be   (one row per block, 256 threads)
// Safe when out aliases a (each thread touches only its own element).
// ---------------------------------------------------------------------------
__global__ void add_ln(const float* __restrict__ a, const float* __restrict__ rsd,
                       const float* __restrict__ g, const float* __restrict__ be,
                       float* __restrict__ out) {
    __shared__ float r1[4], r2[4];
    const int row = blockIdx.x, t = threadIdx.x;
    const float v = a[(size_t)row * D + t] + rsd[(size_t)row * D + t];
    float s1 = v, s2 = v * v;
#pragma unroll
    for (int o = 32; o > 0; o >>= 1) {
        s1 += __shfl_down(s1, o, 64);
        s2 += __shfl_down(s2, o, 64);
    }
    if ((t & 63) == 0) { r1[t >> 6] = s1; r2[t >> 6] = s2; }
    __syncthreads();
    float su = r1[0] + r1[1] + r1[2] + r1[3];
    float sq = r2[0] + r2[1] + r2[2] + r2[3];
    float mean = su * (1.0f / D);
    float var = fmaxf(sq * (1.0f / D) - mean * mean, 0.f);
    out[(size_t)row * D + t] = (v - mean) * rsqrtf(var + 1e-5f) * g[t] + be[t];
}

// ---------------------------------------------------------------------------
extern "C" void kernel_launch(void* const* d_in, const int* in_sizes, int n_in,
                              void* d_out, int out_size, void* d_ws, size_t ws_size,
                              hipStream_t stream) {
    const float* src     = (const float*)d_in[0];
    const float* pos     = (const float*)d_in[1];
    const float* w_value = (const float*)d_in[4];
    const float* b_value = (const float*)d_in[5];
    const float* w_off   = (const float*)d_in[6];
    const float* b_off   = (const float*)d_in[7];
    const float* w_attn  = (const float*)d_in[8];
    const float* b_attn  = (const float*)d_in[9];
    const float* w_out   = (const float*)d_in[10];
    const float* b_out   = (const float*)d_in[11];
    const float* w1      = (const float*)d_in[12];
    const float* b1      = (const float*)d_in[13];
    const float* w2      = (const float*)d_in[14];
    const float* b2      = (const float*)d_in[15];
    const float* g1      = (const float*)d_in[16];
    const float* be1     = (const float*)d_in[17];
    const float* g2      = (const float*)d_in[18];
    const float* be2     = (const float*)d_in[19];
    float* out = (float*)d_out;

    // ---- workspace layout (total ~41.5 MB; round-1 proved >=50.1 MB exists) ----
    size_t off = 0;
    auto alloc = [&](size_t bytes) -> char* {
        char* p = (char*)d_ws + off;
        off += (bytes + 255) & ~(size_t)255;
        return p;
    };
    unsigned short* wvT = (unsigned short*)alloc(256 * 256 * 2);
    unsigned short* wqT = (unsigned short*)alloc(384 * 256 * 2);   // w_offT ++ w_attnT
    unsigned short* woT = (unsigned short*)alloc(256 * 256 * 2);
    unsigned short* w1T = (unsigned short*)alloc((size_t)2048 * 256 * 2);
    unsigned short* w2T = (unsigned short*)alloc((size_t)256 * 2048 * 2);
    float* bq           = (float*)alloc(384 * 4);

    // big region: phase-1 buffers; later aliased by half-hidden (hb, 22.28 MB)
    const size_t qout_b = (size_t)MROWS * 384 * 4;        // 16.71 MB
    const size_t val_b  = (size_t)MROWS * 256 * 2;        //  5.57 MB
    const size_t attn_b = (size_t)MROWS * 256 * 2;        //  5.57 MB
    const size_t hbh_b  = (size_t)MROWS * 1024 * 2;       // 22.28 MB (half hidden)
    size_t big_b = qout_b + val_b + attn_b;               // 27.85 MB
    if (hbh_b > big_b) big_b = hbh_b;
    char* big = alloc(big_b);
    float* qout          = (float*)big;
    unsigned short* val  = (unsigned short*)(big + qout_b);
    unsigned short* attn = (unsigned short*)(big + qout_b + val_b);
    unsigned short* hb   = (unsigned short*)big;          // aliases dead phase-1 bufs
    float* xbuf          = (float*)alloc((size_t)MROWS * 256 * 4);   // 11.14 MB

    // ---- weight prep: transpose + bf16 ----
    transpose_bf16<<<dim3(8, 8),  256, 0, stream>>>(w_value, wvT, 256, 256);
    transpose_bf16<<<dim3(8, 8),  256, 0, stream>>>(w_off,   wqT, 256, 256);
    transpose_bf16<<<dim3(4, 8),  256, 0, stream>>>(w_attn,  wqT + 256 * 256, 256, 128);
    transpose_bf16<<<dim3(8, 8),  256, 0, stream>>>(w_out,   woT, 256, 256);
    transpose_bf16<<<dim3(64, 8), 256, 0, stream>>>(w1,      w1T, 256, 2048);
    transpose_bf16<<<dim3(8, 64), 256, 0, stream>>>(w2,      w2T, 2048, 256);
    concat_bias<<<1, 384, 0, stream>>>(b_off, b_attn, bq);

    // ---- attention ----
    // qout = (src+pos) @ [w_off | w_attn] + bias   (M x 384, fp32)
    mfma_gemm<true, true, false, false, false><<<dim3(85, 3), 256, 0, stream>>>(
        src, pos, wqT, bq, qout, 384, 256, 256, 256);
    // val = src @ w_value + b_value   (M x 256, bf16)
    mfma_gemm<true, false, false, true, false><<<dim3(85, 2), 256, 0, stream>>>(
        src, nullptr, wvT, b_value, val, 256, 256, 256, 256);
    sampler<<<MROWS, 256, 0, stream>>>(val, qout, attn);
    // proj = attn @ w_out + b_out -> d_out (fp32)
    mfma_gemm<false, false, false, false, false><<<dim3(85, 2), 256, 0, stream>>>(
        attn, nullptr, woT, b_out, out, 256, 256, 256, 256);
    // x = LN(proj + src) -> xbuf
    add_ln<<<MROWS, 256, 0, stream>>>(out, src, g1, be1, xbuf);

    // ---- FFN, split into two 1024-wide halves (workspace bound) ----
    // half a: hb = relu(xbuf @ w1[:, :1024] + b1[:1024])
    mfma_gemm<true, false, true, true, false><<<dim3(85, 8), 256, 0, stream>>>(
        xbuf, nullptr, w1T, b1, hb, 1024, 256, 256, 256);
    // out = hb @ w2[:1024, :] + b2
    mfma_gemm<false, false, false, false, false><<<dim3(85, 2), 256, 0, stream>>>(
        hb, nullptr, w2T, b2, out, 256, 1024, 1024, 2048);
    // half b: hb = relu(xbuf @ w1[:, 1024:] + b1[1024:])
    mfma_gemm<true, false, true, true, false><<<dim3(85, 8), 256, 0, stream>>>(
        xbuf, nullptr, w1T + (size_t)1024 * 256, b1 + 1024, hb, 1024, 256, 256, 256);
    // out += hb @ w2[1024:, :]
    mfma_gemm<false, false, false, false, true><<<dim3(85, 2), 256, 0, stream>>>(
        hb, nullptr, w2T + 1024, nullptr, out, 256, 1024, 1024, 2048);
    // out = LN(out + xbuf) -> d_out (in place)
    add_ln<<<MROWS, 256, 0, stream>>>(out, xbuf, g2, be2, out);
}

// Round 5
// 296.162 us; speedup vs baseline: 2.9630x; 1.2210x over previous
//
#include <hip/hip_runtime.h>
#include <math.h>

#define D 256
#define NH 8
#define NL 4
#define NP 4
#define DFF 2048
#define HD 32
#define BB 2
#define LEN 5440
#define MROWS (BB * LEN)   // 10880 = 85 * 128 exactly

typedef __attribute__((ext_vector_type(8))) short short8;
typedef __attribute__((ext_vector_type(4))) float f32x4;
typedef unsigned int uint32;

__device__ __forceinline__ unsigned short f2bf(float f) {
    uint32 u = __float_as_uint(f);
    u += 0x7FFF + ((u >> 16) & 1);           // round-to-nearest-even
    return (unsigned short)(u >> 16);
}
__device__ __forceinline__ float bf2f(unsigned short h) {
    return __uint_as_float(((uint32)h) << 16);
}
__device__ __forceinline__ uint32 pack2(float a, float b) {
    return (uint32)f2bf(a) | ((uint32)f2bf(b) << 16);
}

// ---------------------------------------------------------------------------
// prep: all weight transposes (fp32 [KxN] -> bf16 [NxK]) + bias concat,
// in ONE launch. Tile map (32x32 tiles, 256 thr = 32x8):
//   [0,64)    w_value -> wqvT rows 0..255     (K=256,N=256)
//   [64,128)  w_off   -> wqvT rows 256..511   (K=256,N=256)
//   [128,160) w_attn  -> wqvT rows 512..639   (K=256,N=128)
//   [160,224) w_out   -> woT                  (K=256,N=256)
//   [224,736) w1      -> w1T                  (K=256,N=2048)
//   [736,1248) w2     -> w2T                  (K=2048,N=256)
//   1248      bias concat [b_value|b_off|b_attn] -> bqv[640]
// ---------------------------------------------------------------------------
__global__ void prep(const float* __restrict__ w_value, const float* __restrict__ w_off,
                     const float* __restrict__ w_attn, const float* __restrict__ w_out,
                     const float* __restrict__ w1, const float* __restrict__ w2,
                     const float* __restrict__ b_value, const float* __restrict__ b_off,
                     const float* __restrict__ b_attn,
                     unsigned short* __restrict__ wqvT, unsigned short* __restrict__ woT,
                     unsigned short* __restrict__ w1T, unsigned short* __restrict__ w2T,
                     float* __restrict__ bqv) {
    const int blk = blockIdx.x;
    if (blk >= 1248) {
        for (int i = threadIdx.x; i < 640; i += 256)
            bqv[i] = (i < 256) ? b_value[i] : (i < 512 ? b_off[i - 256] : b_attn[i - 512]);
        return;
    }
    const float* W; unsigned short* WT; int K, N, tid;
    if (blk < 64)       { W = w_value; WT = wqvT;             K = 256;  N = 256;  tid = blk; }
    else if (blk < 128) { W = w_off;   WT = wqvT + 256 * 256; K = 256;  N = 256;  tid = blk - 64; }
    else if (blk < 160) { W = w_attn;  WT = wqvT + 512 * 256; K = 256;  N = 128;  tid = blk - 128; }
    else if (blk < 224) { W = w_out;   WT = woT;              K = 256;  N = 256;  tid = blk - 160; }
    else if (blk < 736) { W = w1;      WT = w1T;              K = 256;  N = 2048; tid = blk - 224; }
    else                { W = w2;      WT = w2T;              K = 2048; N = 256;  tid = blk - 736; }
    const int ntx = N >> 5;
    const int nb = (tid % ntx) * 32, kb = (tid / ntx) * 32;

    __shared__ float tile[32][33];
    const int tx = threadIdx.x & 31, ty = threadIdx.x >> 5;
#pragma unroll
    for (int i = 0; i < 32; i += 8)
        tile[ty + i][tx] = W[(size_t)(kb + ty + i) * N + nb + tx];
    __syncthreads();
#pragma unroll
    for (int i = 0; i < 32; i += 8)
        WT[(size_t)(nb + ty + i) * K + kb + tx] = f2bf(tile[tx][ty + i]);
}

// ---------------------------------------------------------------------------
// Generic bf16 MFMA GEMM: C[M x N] = A[M x K] @ BT[N x K]^T + bias (or +C)
//   tile 128x128, block 256 thr = 4 waves (2x2 of 64x64), BK=32
//   MFMA 16x16x32_bf16: A[m=lane&15][k=quad*8+j], B[n=lane&15][k=quad*8+j],
//   C/D col=lane&15 row=quad*4+reg  [verified]
// ---------------------------------------------------------------------------
template <bool A_FP32, bool ADD_P, bool RELU, bool OUT_BF16, bool ACCUM>
__global__ __launch_bounds__(256) void mfma_gemm(
        const void* __restrict__ Av, const float* __restrict__ P,
        const unsigned short* __restrict__ BT, const float* __restrict__ bias,
        void* __restrict__ Cv, int N, int K, int lda, int ldb) {
    __shared__ unsigned short Ash[128][40];
    __shared__ unsigned short Bsh[128][40];

    const int t = threadIdx.x;
    const int wave = t >> 6, lane = t & 63;
    const int wr = wave >> 1, wc = wave & 1;
    const int lrow = lane & 15, quad = lane >> 4;
    const int row0 = blockIdx.x * 128;
    const int col0 = blockIdx.y * 128;

    const int srow = t >> 1;
    const int cb = (t & 1) * 16;

    f32x4 acc[4][4];
#pragma unroll
    for (int i = 0; i < 4; i++)
#pragma unroll
        for (int j = 0; j < 4; j++) acc[i][j] = (f32x4){0.f, 0.f, 0.f, 0.f};

    for (int kb = 0; kb < K; kb += 32) {
        __syncthreads();
        if (A_FP32) {
            const float* ap = (const float*)Av + (size_t)(row0 + srow) * lda + kb + cb;
            float4 f0 = *(const float4*)(ap + 0);
            float4 f1 = *(const float4*)(ap + 4);
            float4 f2 = *(const float4*)(ap + 8);
            float4 f3 = *(const float4*)(ap + 12);
            if (ADD_P) {
                const float* pp = P + (size_t)(row0 + srow) * lda + kb + cb;
                float4 p0 = *(const float4*)(pp + 0);
                float4 p1 = *(const float4*)(pp + 4);
                float4 p2 = *(const float4*)(pp + 8);
                float4 p3 = *(const float4*)(pp + 12);
                f0.x += p0.x; f0.y += p0.y; f0.z += p0.z; f0.w += p0.w;
                f1.x += p1.x; f1.y += p1.y; f1.z += p1.z; f1.w += p1.w;
                f2.x += p2.x; f2.y += p2.y; f2.z += p2.z; f2.w += p2.w;
                f3.x += p3.x; f3.y += p3.y; f3.z += p3.z; f3.w += p3.w;
            }
            uint4 u0 = make_uint4(pack2(f0.x, f0.y), pack2(f0.z, f0.w),
                                  pack2(f1.x, f1.y), pack2(f1.z, f1.w));
            uint4 u1 = make_uint4(pack2(f2.x, f2.y), pack2(f2.z, f2.w),
                                  pack2(f3.x, f3.y), pack2(f3.z, f3.w));
            *(uint4*)&Ash[srow][cb + 0] = u0;
            *(uint4*)&Ash[srow][cb + 8] = u1;
        } else {
            const unsigned short* ap = (const unsigned short*)Av + (size_t)(row0 + srow) * lda + kb + cb;
            *(uint4*)&Ash[srow][cb + 0] = *(const uint4*)(ap + 0);
            *(uint4*)&Ash[srow][cb + 8] = *(const uint4*)(ap + 8);
        }
        {
            const unsigned short* bp = BT + (size_t)(col0 + srow) * ldb + kb + cb;
            *(uint4*)&Bsh[srow][cb + 0] = *(const uint4*)(bp + 0);
            *(uint4*)&Bsh[srow][cb + 8] = *(const uint4*)(bp + 8);
        }
        __syncthreads();

        short8 af[4], bfr[4];
#pragma unroll
        for (int mt = 0; mt < 4; mt++)
            af[mt] = *(const short8*)&Ash[wr * 64 + mt * 16 + lrow][quad * 8];
#pragma unroll
        for (int nt = 0; nt < 4; nt++)
            bfr[nt] = *(const short8*)&Bsh[wc * 64 + nt * 16 + lrow][quad * 8];
#pragma unroll
        for (int mt = 0; mt < 4; mt++)
#pragma unroll
            for (int nt = 0; nt < 4; nt++)
                acc[mt][nt] = __builtin_amdgcn_mfma_f32_16x16x32_bf16(
                    af[mt], bfr[nt], acc[mt][nt], 0, 0, 0);
    }

#pragma unroll
    for (int nt = 0; nt < 4; nt++) {
        const int col = col0 + wc * 64 + nt * 16 + lrow;
        const float bv = ACCUM ? 0.f : bias[col];
#pragma unroll
        for (int mt = 0; mt < 4; mt++) {
            f32x4 a = acc[mt][nt];
#pragma unroll
            for (int r = 0; r < 4; r++) {
                const int row = row0 + wr * 64 + mt * 16 + quad * 4 + r;
                float v = a[r] + bv;
                if (ACCUM) v += ((const float*)Cv)[(size_t)row * N + col];
                if (RELU) v = fmaxf(v, 0.f);
                if (OUT_BF16)
                    ((unsigned short*)Cv)[(size_t)row * N + col] = f2bf(v);
                else
                    ((float*)Cv)[(size_t)row * N + col] = v;
            }
        }
    }
}

// ---------------------------------------------------------------------------
// Merged value+query GEMM: N=640, BT = [w_valueT | w_offT | w_attnT].
// col < 256  -> val (bf16, stride 256);  col >= 256 -> qout (fp32, stride 384).
// A = src; +pos only for the query half (col0 >= 256).
// ---------------------------------------------------------------------------
__global__ __launch_bounds__(256) void qv_gemm(
        const float* __restrict__ src, const float* __restrict__ pos,
        const unsigned short* __restrict__ BT, const float* __restrict__ bias,
        unsigned short* __restrict__ val, float* __restrict__ qout) {
    __shared__ unsigned short Ash[128][40];
    __shared__ unsigned short Bsh[128][40];

    const int t = threadIdx.x;
    const int wave = t >> 6, lane = t & 63;
    const int wr = wave >> 1, wc = wave & 1;
    const int lrow = lane & 15, quad = lane >> 4;
    const int row0 = blockIdx.x * 128;
    const int col0 = blockIdx.y * 128;
    const bool addp = (col0 >= 256);

    const int srow = t >> 1;
    const int cb = (t & 1) * 16;

    f32x4 acc[4][4];
#pragma unroll
    for (int i = 0; i < 4; i++)
#pragma unroll
        for (int j = 0; j < 4; j++) acc[i][j] = (f32x4){0.f, 0.f, 0.f, 0.f};

    for (int kb = 0; kb < 256; kb += 32) {
        __syncthreads();
        {
            const float* ap = src + (size_t)(row0 + srow) * 256 + kb + cb;
            float4 f0 = *(const float4*)(ap + 0);
            float4 f1 = *(const float4*)(ap + 4);
            float4 f2 = *(const float4*)(ap + 8);
            float4 f3 = *(const float4*)(ap + 12);
            if (addp) {
                const float* pp = pos + (size_t)(row0 + srow) * 256 + kb + cb;
                float4 p0 = *(const float4*)(pp + 0);
                float4 p1 = *(const float4*)(pp + 4);
                float4 p2 = *(const float4*)(pp + 8);
                float4 p3 = *(const float4*)(pp + 12);
                f0.x += p0.x; f0.y += p0.y; f0.z += p0.z; f0.w += p0.w;
                f1.x += p1.x; f1.y += p1.y; f1.z += p1.z; f1.w += p1.w;
                f2.x += p2.x; f2.y += p2.y; f2.z += p2.z; f2.w += p2.w;
                f3.x += p3.x; f3.y += p3.y; f3.z += p3.z; f3.w += p3.w;
            }
            uint4 u0 = make_uint4(pack2(f0.x, f0.y), pack2(f0.z, f0.w),
                                  pack2(f1.x, f1.y), pack2(f1.z, f1.w));
            uint4 u1 = make_uint4(pack2(f2.x, f2.y), pack2(f2.z, f2.w),
                                  pack2(f3.x, f3.y), pack2(f3.z, f3.w));
            *(uint4*)&Ash[srow][cb + 0] = u0;
            *(uint4*)&Ash[srow][cb + 8] = u1;
        }
        {
            const unsigned short* bp = BT + (size_t)(col0 + srow) * 256 + kb + cb;
            *(uint4*)&Bsh[srow][cb + 0] = *(const uint4*)(bp + 0);
            *(uint4*)&Bsh[srow][cb + 8] = *(const uint4*)(bp + 8);
        }
        __syncthreads();

        short8 af[4], bfr[4];
#pragma unroll
        for (int mt = 0; mt < 4; mt++)
            af[mt] = *(const short8*)&Ash[wr * 64 + mt * 16 + lrow][quad * 8];
#pragma unroll
        for (int nt = 0; nt < 4; nt++)
            bfr[nt] = *(const short8*)&Bsh[wc * 64 + nt * 16 + lrow][quad * 8];
#pragma unroll
        for (int mt = 0; mt < 4; mt++)
#pragma unroll
            for (int nt = 0; nt < 4; nt++)
                acc[mt][nt] = __builtin_amdgcn_mfma_f32_16x16x32_bf16(
                    af[mt], bfr[nt], acc[mt][nt], 0, 0, 0);
    }

#pragma unroll
    for (int nt = 0; nt < 4; nt++) {
        const int col = col0 + wc * 64 + nt * 16 + lrow;
        const float bv = bias[col];
#pragma unroll
        for (int mt = 0; mt < 4; mt++) {
            f32x4 a = acc[mt][nt];
#pragma unroll
            for (int r = 0; r < 4; r++) {
                const int row = row0 + wr * 64 + mt * 16 + quad * 4 + r;
                float v = a[r] + bv;
                if (col < 256)
                    val[(size_t)row * 256 + col] = f2bf(v);
                else
                    qout[(size_t)row * 384 + (col - 256)] = v;
            }
        }
    }
}

// ---------------------------------------------------------------------------
// Two-phase sampler.
// Phase 1 (t<128, one thread per (h,p)): 16-lane shfl softmax + corner
//   indices/weights, packed int4/float4 -> LDS.
// Phase 2 (all 256, (h,d)): per point 2x broadcast ds_read_b128 + 4 gathers.
// ---------------------------------------------------------------------------
__global__ void sampler(const unsigned short* __restrict__ val, const float* __restrict__ qout,
                        unsigned short* __restrict__ out) {
    __shared__ __align__(16) int   sIdx[128][4];
    __shared__ __align__(16) float sW[128][4];
    const int bq = blockIdx.x;
    const int b = bq / LEN, q = bq % LEN;
    const int t = threadIdx.x;

    if (t < 128) {
        const int h = t >> 4, p = t & 15;
        const int l = p >> 2;

        float refx, refy;
        if (q < 4096) {
            int rq = q >> 6, cq = q & 63;
            refx = (cq + 0.5f) * (1.0f / 64.0f);
            refy = (rq + 0.5f) * (1.0f / 64.0f);
        } else if (q < 5120) {
            int qq = q - 4096;
            int rq = qq >> 5, cq = qq & 31;
            refx = (cq + 0.5f) * (1.0f / 32.0f);
            refy = (rq + 0.5f) * (1.0f / 32.0f);
        } else if (q < 5376) {
            int qq = q - 5120;
            int rq = qq >> 4, cq = qq & 15;
            refx = (cq + 0.5f) * (1.0f / 16.0f);
            refy = (rq + 0.5f) * (1.0f / 16.0f);
        } else {
            int qq = q - 5376;
            int rq = qq >> 3, cq = qq & 7;
            refx = (cq + 0.5f) * (1.0f / 8.0f);
            refy = (rq + 0.5f) * (1.0f / 8.0f);
        }

        // softmax over this head's 16 logits (t maps exactly to h*16+p)
        float lv = qout[(size_t)bq * 384 + 256 + t];
        float mx = lv;
#pragma unroll
        for (int o = 1; o < 16; o <<= 1) mx = fmaxf(mx, __shfl_xor(mx, o, 16));
        float e = expf(lv - mx);
        float s = e;
#pragma unroll
        for (int o = 1; o < 16; o <<= 1) s += __shfl_xor(s, o, 16);
        const float aw = e / s;

        const float ox = qout[(size_t)bq * 384 + h * 32 + p * 2 + 0];
        const float oy = qout[(size_t)bq * 384 + h * 32 + p * 2 + 1];

        const int LST[4] = {0, 4096, 5120, 5376};
        const int WW = 64 >> l;
        const float rw = 1.0f / (float)WW;

        float x = (refx + ox * rw) * (float)WW - 0.5f;
        float y = (refy + oy * rw) * (float)WW - 0.5f;
        float x0f = floorf(x), y0f = floorf(y);
        float dx = x - x0f, dy = y - y0f;
        int x0 = (int)x0f, y0 = (int)y0f;

        const int base = (b * LEN + LST[l]) * 256 + h * 32;
        int4 iv; float4 wv;
        {
            int xs[2] = {x0, x0 + 1}, ys[2] = {y0, y0 + 1};
            float wx[2] = {1.f - dx, dx}, wy[2] = {1.f - dy, dy};
            int ic[4]; float wc4[4];
#pragma unroll
            for (int cy = 0; cy < 2; cy++)
#pragma unroll
                for (int cx = 0; cx < 2; cx++) {
                    int xi = xs[cx], yi = ys[cy];
                    bool vld = (xi >= 0) && (xi < WW) && (yi >= 0) && (yi < WW);
                    int xc = min(max(xi, 0), WW - 1);
                    int yc = min(max(yi, 0), WW - 1);
                    ic[cy * 2 + cx] = base + (yc * WW + xc) * 256;
                    wc4[cy * 2 + cx] = vld ? wx[cx] * wy[cy] * aw : 0.f;
                }
            iv = make_int4(ic[0], ic[1], ic[2], ic[3]);
            wv = make_float4(wc4[0], wc4[1], wc4[2], wc4[3]);
        }
        *(int4*)&sIdx[t][0] = iv;
        *(float4*)&sW[t][0] = wv;
    }
    __syncthreads();

    const int h = t >> 5, d = t & 31;
    const unsigned short* vald = val + d;
    float acc = 0.f;
#pragma unroll 4
    for (int p = 0; p < 16; p++) {
        const int r = h * 16 + p;
        int4 iv = *(const int4*)&sIdx[r][0];
        float4 wv = *(const float4*)&sW[r][0];
        acc += bf2f(vald[iv.x]) * wv.x;
        acc += bf2f(vald[iv.y]) * wv.y;
        acc += bf2f(vald[iv.z]) * wv.z;
        acc += bf2f(vald[iv.w]) * wv.w;
    }
    out[(size_t)bq * D + h * HD + d] = f2bf(acc);
}

// ---------------------------------------------------------------------------
// out = LayerNorm(a + rsd) * g + be   (one row per block, 256 threads)
// ---------------------------------------------------------------------------
__global__ void add_ln(const float* __restrict__ a, const float* __restrict__ rsd,
                       const float* __restrict__ g, const float* __restrict__ be,
                       float* __restrict__ out) {
    __shared__ float r1[4], r2[4];
    const int row = blockIdx.x, t = threadIdx.x;
    const float v = a[(size_t)row * D + t] + rsd[(size_t)row * D + t];
    float s1 = v, s2 = v * v;
#pragma unroll
    for (int o = 32; o > 0; o >>= 1) {
        s1 += __shfl_down(s1, o, 64);
        s2 += __shfl_down(s2, o, 64);
    }
    if ((t & 63) == 0) { r1[t >> 6] = s1; r2[t >> 6] = s2; }
    __syncthreads();
    float su = r1[0] + r1[1] + r1[2] + r1[3];
    float sq = r2[0] + r2[1] + r2[2] + r2[3];
    float mean = su * (1.0f / D);
    float var = fmaxf(sq * (1.0f / D) - mean * mean, 0.f);
    out[(size_t)row * D + t] = (v - mean) * rsqrtf(var + 1e-5f) * g[t] + be[t];
}

// ---------------------------------------------------------------------------
extern "C" void kernel_launch(void* const* d_in, const int* in_sizes, int n_in,
                              void* d_out, int out_size, void* d_ws, size_t ws_size,
                              hipStream_t stream) {
    const float* src     = (const float*)d_in[0];
    const float* pos     = (const float*)d_in[1];
    const float* w_value = (const float*)d_in[4];
    const float* b_value = (const float*)d_in[5];
    const float* w_off   = (const float*)d_in[6];
    const float* b_off   = (const float*)d_in[7];
    const float* w_attn  = (const float*)d_in[8];
    const float* b_attn  = (const float*)d_in[9];
    const float* w_out   = (const float*)d_in[10];
    const float* b_out   = (const float*)d_in[11];
    const float* w1      = (const float*)d_in[12];
    const float* b1      = (const float*)d_in[13];
    const float* w2      = (const float*)d_in[14];
    const float* b2      = (const float*)d_in[15];
    const float* g1      = (const float*)d_in[16];
    const float* be1     = (const float*)d_in[17];
    const float* g2      = (const float*)d_in[18];
    const float* be2     = (const float*)d_in[19];
    float* out = (float*)d_out;

    // ---- workspace layout (~41.5 MB; round-1 proved >=50.1 MB exists) ----
    size_t off = 0;
    auto alloc = [&](size_t bytes) -> char* {
        char* p = (char*)d_ws + off;
        off += (bytes + 255) & ~(size_t)255;
        return p;
    };
    unsigned short* wqvT = (unsigned short*)alloc((size_t)640 * 256 * 2);  // [wv|woff|wattn]
    unsigned short* woT  = (unsigned short*)alloc(256 * 256 * 2);
    unsigned short* w1T  = (unsigned short*)alloc((size_t)2048 * 256 * 2);
    unsigned short* w2T  = (unsigned short*)alloc((size_t)256 * 2048 * 2);
    float* bqv           = (float*)alloc(640 * 4);

    const size_t qout_b = (size_t)MROWS * 384 * 4;        // 16.71 MB
    const size_t val_b  = (size_t)MROWS * 256 * 2;        //  5.57 MB
    const size_t attn_b = (size_t)MROWS * 256 * 2;        //  5.57 MB
    const size_t hbh_b  = (size_t)MROWS * 1024 * 2;       // 22.28 MB (half hidden)
    size_t big_b = qout_b + val_b + attn_b;               // 27.85 MB
    if (hbh_b > big_b) big_b = hbh_b;
    char* big = alloc(big_b);
    float* qout          = (float*)big;
    unsigned short* val  = (unsigned short*)(big + qout_b);
    unsigned short* attn = (unsigned short*)(big + qout_b + val_b);
    unsigned short* hb   = (unsigned short*)big;          // aliases dead phase-1 bufs
    float* xbuf          = (float*)alloc((size_t)MROWS * 256 * 4);   // 11.14 MB

    // ---- weight prep (single launch) ----
    prep<<<1249, 256, 0, stream>>>(w_value, w_off, w_attn, w_out, w1, w2,
                                   b_value, b_off, b_attn, wqvT, woT, w1T, w2T, bqv);

    // ---- attention ----
    // [val | qout] = [src | src+pos] @ wqvT + bqv   (N=640 merged)
    qv_gemm<<<dim3(85, 5), 256, 0, stream>>>(src, pos, wqvT, bqv, val, qout);
    sampler<<<MROWS, 256, 0, stream>>>(val, qout, attn);
    // proj = attn @ w_out + b_out -> d_out (fp32)
    mfma_gemm<false, false, false, false, false><<<dim3(85, 2), 256, 0, stream>>>(
        attn, nullptr, woT, b_out, out, 256, 256, 256, 256);
    // x = LN(proj + src) -> xbuf
    add_ln<<<MROWS, 256, 0, stream>>>(out, src, g1, be1, xbuf);

    // ---- FFN, two 1024-wide halves (workspace bound) ----
    mfma_gemm<true, false, true, true, false><<<dim3(85, 8), 256, 0, stream>>>(
        xbuf, nullptr, w1T, b1, hb, 1024, 256, 256, 256);
    mfma_gemm<false, false, false, false, false><<<dim3(85, 2), 256, 0, stream>>>(
        hb, nullptr, w2T, b2, out, 256, 1024, 1024, 2048);
    mfma_gemm<true, false, true, true, false><<<dim3(85, 8), 256, 0, stream>>>(
        xbuf, nullptr, w1T + (size_t)1024 * 256, b1 + 1024, hb, 1024, 256, 256, 256);
    mfma_gemm<false, false, false, false, true><<<dim3(85, 2), 256, 0, stream>>>(
        hb, nullptr, w2T + 1024, nullptr, out, 256, 1024, 1024, 2048);
    // out = LN(out + xbuf) -> d_out (in place)
    add_ln<<<MROWS, 256, 0, stream>>>(out, xbuf, g2, be2, out);
}

// Round 6
// 261.108 us; speedup vs baseline: 3.3608x; 1.1343x over previous
//
#include <hip/hip_runtime.h>
#include <math.h>

#define D 256
#define NH 8
#define NL 4
#define NP 4
#define DFF 2048
#define HD 32
#define BB 2
#define LEN 5440
#define MROWS (BB * LEN)   // 10880 = 85 * 128 exactly

typedef __attribute__((ext_vector_type(8))) short short8;
typedef __attribute__((ext_vector_type(4))) float f32x4;
typedef unsigned int uint32;

__device__ __forceinline__ unsigned short f2bf(float f) {
    uint32 u = __float_as_uint(f);
    u += 0x7FFF + ((u >> 16) & 1);           // round-to-nearest-even
    return (unsigned short)(u >> 16);
}
__device__ __forceinline__ float bf2f(unsigned short h) {
    return __uint_as_float(((uint32)h) << 16);
}
__device__ __forceinline__ uint32 pack2(float a, float b) {
    return (uint32)f2bf(a) | ((uint32)f2bf(b) << 16);
}

// ---------------------------------------------------------------------------
// prep: all weight transposes (fp32 [KxN] -> bf16 [NxK]) + bias concat.
// ---------------------------------------------------------------------------
__global__ void prep(const float* __restrict__ w_value, const float* __restrict__ w_off,
                     const float* __restrict__ w_attn, const float* __restrict__ w_out,
                     const float* __restrict__ w1, const float* __restrict__ w2,
                     const float* __restrict__ b_value, const float* __restrict__ b_off,
                     const float* __restrict__ b_attn,
                     unsigned short* __restrict__ wqvT, unsigned short* __restrict__ woT,
                     unsigned short* __restrict__ w1T, unsigned short* __restrict__ w2T,
                     float* __restrict__ bqv) {
    const int blk = blockIdx.x;
    if (blk >= 1248) {
        for (int i = threadIdx.x; i < 640; i += 256)
            bqv[i] = (i < 256) ? b_value[i] : (i < 512 ? b_off[i - 256] : b_attn[i - 512]);
        return;
    }
    const float* W; unsigned short* WT; int K, N, tid;
    if (blk < 64)       { W = w_value; WT = wqvT;             K = 256;  N = 256;  tid = blk; }
    else if (blk < 128) { W = w_off;   WT = wqvT + 256 * 256; K = 256;  N = 256;  tid = blk - 64; }
    else if (blk < 160) { W = w_attn;  WT = wqvT + 512 * 256; K = 256;  N = 128;  tid = blk - 128; }
    else if (blk < 224) { W = w_out;   WT = woT;              K = 256;  N = 256;  tid = blk - 160; }
    else if (blk < 736) { W = w1;      WT = w1T;              K = 256;  N = 2048; tid = blk - 224; }
    else                { W = w2;      WT = w2T;              K = 2048; N = 256;  tid = blk - 736; }
    const int ntx = N >> 5;
    const int nb = (tid % ntx) * 32, kb = (tid / ntx) * 32;

    __shared__ float tile[32][33];
    const int tx = threadIdx.x & 31, ty = threadIdx.x >> 5;
#pragma unroll
    for (int i = 0; i < 32; i += 8)
        tile[ty + i][tx] = W[(size_t)(kb + ty + i) * N + nb + tx];
    __syncthreads();
#pragma unroll
    for (int i = 0; i < 32; i += 8)
        WT[(size_t)(nb + ty + i) * K + kb + tx] = f2bf(tile[tx][ty + i]);
}

// ---------------------------------------------------------------------------
// Generic bf16 MFMA GEMM (used for ffn1): C = A @ BT^T + bias, 128x128 tile.
// ---------------------------------------------------------------------------
template <bool A_FP32, bool RELU, bool OUT_BF16>
__global__ __launch_bounds__(256) void mfma_gemm(
        const void* __restrict__ Av,
        const unsigned short* __restrict__ BT, const float* __restrict__ bias,
        void* __restrict__ Cv, int N, int K, int lda, int ldb) {
    __shared__ unsigned short Ash[128][40];
    __shared__ unsigned short Bsh[128][40];

    const int t = threadIdx.x;
    const int wave = t >> 6, lane = t & 63;
    const int wr = wave >> 1, wc = wave & 1;
    const int lrow = lane & 15, quad = lane >> 4;
    const int row0 = blockIdx.x * 128;
    const int col0 = blockIdx.y * 128;

    const int srow = t >> 1;
    const int cb = (t & 1) * 16;

    f32x4 acc[4][4];
#pragma unroll
    for (int i = 0; i < 4; i++)
#pragma unroll
        for (int j = 0; j < 4; j++) acc[i][j] = (f32x4){0.f, 0.f, 0.f, 0.f};

    for (int kb = 0; kb < K; kb += 32) {
        __syncthreads();
        if (A_FP32) {
            const float* ap = (const float*)Av + (size_t)(row0 + srow) * lda + kb + cb;
            float4 f0 = *(const float4*)(ap + 0);
            float4 f1 = *(const float4*)(ap + 4);
            float4 f2 = *(const float4*)(ap + 8);
            float4 f3 = *(const float4*)(ap + 12);
            uint4 u0 = make_uint4(pack2(f0.x, f0.y), pack2(f0.z, f0.w),
                                  pack2(f1.x, f1.y), pack2(f1.z, f1.w));
            uint4 u1 = make_uint4(pack2(f2.x, f2.y), pack2(f2.z, f2.w),
                                  pack2(f3.x, f3.y), pack2(f3.z, f3.w));
            *(uint4*)&Ash[srow][cb + 0] = u0;
            *(uint4*)&Ash[srow][cb + 8] = u1;
        } else {
            const unsigned short* ap = (const unsigned short*)Av + (size_t)(row0 + srow) * lda + kb + cb;
            *(uint4*)&Ash[srow][cb + 0] = *(const uint4*)(ap + 0);
            *(uint4*)&Ash[srow][cb + 8] = *(const uint4*)(ap + 8);
        }
        {
            const unsigned short* bp = BT + (size_t)(col0 + srow) * ldb + kb + cb;
            *(uint4*)&Bsh[srow][cb + 0] = *(const uint4*)(bp + 0);
            *(uint4*)&Bsh[srow][cb + 8] = *(const uint4*)(bp + 8);
        }
        __syncthreads();

        short8 af[4], bfr[4];
#pragma unroll
        for (int mt = 0; mt < 4; mt++)
            af[mt] = *(const short8*)&Ash[wr * 64 + mt * 16 + lrow][quad * 8];
#pragma unroll
        for (int nt = 0; nt < 4; nt++)
            bfr[nt] = *(const short8*)&Bsh[wc * 64 + nt * 16 + lrow][quad * 8];
#pragma unroll
        for (int mt = 0; mt < 4; mt++)
#pragma unroll
            for (int nt = 0; nt < 4; nt++)
                acc[mt][nt] = __builtin_amdgcn_mfma_f32_16x16x32_bf16(
                    af[mt], bfr[nt], acc[mt][nt], 0, 0, 0);
    }

#pragma unroll
    for (int nt = 0; nt < 4; nt++) {
        const int col = col0 + wc * 64 + nt * 16 + lrow;
        const float bv = bias[col];
#pragma unroll
        for (int mt = 0; mt < 4; mt++) {
            f32x4 a = acc[mt][nt];
#pragma unroll
            for (int r = 0; r < 4; r++) {
                const int row = row0 + wr * 64 + mt * 16 + quad * 4 + r;
                float v = a[r] + bv;
                if (RELU) v = fmaxf(v, 0.f);
                if (OUT_BF16)
                    ((unsigned short*)Cv)[(size_t)row * N + col] = f2bf(v);
                else
                    ((float*)Cv)[(size_t)row * N + col] = v;
            }
        }
    }
}

// ---------------------------------------------------------------------------
// Split-K GEMM: partial[z] = A[:, z*KC:(z+1)*KC] @ BT[:, z*KC:...]^T
//   A bf16 (lda), BT bf16 (ldb), N=256 fixed, no bias (added in add_ln2).
//   grid (M/128, 2, KSPLIT); partial z is an M x 256 fp32 buffer.
// ---------------------------------------------------------------------------
__global__ __launch_bounds__(256) void splitk_gemm(
        const unsigned short* __restrict__ A, const unsigned short* __restrict__ BT,
        float* __restrict__ part, int KC, int lda, int ldb) {
    __shared__ unsigned short Ash[128][40];
    __shared__ unsigned short Bsh[128][40];

    const int t = threadIdx.x;
    const int wave = t >> 6, lane = t & 63;
    const int wr = wave >> 1, wc = wave & 1;
    const int lrow = lane & 15, quad = lane >> 4;
    const int row0 = blockIdx.x * 128;
    const int col0 = blockIdx.y * 128;
    const int koff = blockIdx.z * KC;
    float* __restrict__ C = part + (size_t)blockIdx.z * MROWS * 256;

    const int srow = t >> 1;
    const int cb = (t & 1) * 16;

    f32x4 acc[4][4];
#pragma unroll
    for (int i = 0; i < 4; i++)
#pragma unroll
        for (int j = 0; j < 4; j++) acc[i][j] = (f32x4){0.f, 0.f, 0.f, 0.f};

    for (int kb = 0; kb < KC; kb += 32) {
        __syncthreads();
        {
            const unsigned short* ap = A + (size_t)(row0 + srow) * lda + koff + kb + cb;
            *(uint4*)&Ash[srow][cb + 0] = *(const uint4*)(ap + 0);
            *(uint4*)&Ash[srow][cb + 8] = *(const uint4*)(ap + 8);
        }
        {
            const unsigned short* bp = BT + (size_t)(col0 + srow) * ldb + koff + kb + cb;
            *(uint4*)&Bsh[srow][cb + 0] = *(const uint4*)(bp + 0);
            *(uint4*)&Bsh[srow][cb + 8] = *(const uint4*)(bp + 8);
        }
        __syncthreads();

        short8 af[4], bfr[4];
#pragma unroll
        for (int mt = 0; mt < 4; mt++)
            af[mt] = *(const short8*)&Ash[wr * 64 + mt * 16 + lrow][quad * 8];
#pragma unroll
        for (int nt = 0; nt < 4; nt++)
            bfr[nt] = *(const short8*)&Bsh[wc * 64 + nt * 16 + lrow][quad * 8];
#pragma unroll
        for (int mt = 0; mt < 4; mt++)
#pragma unroll
            for (int nt = 0; nt < 4; nt++)
                acc[mt][nt] = __builtin_amdgcn_mfma_f32_16x16x32_bf16(
                    af[mt], bfr[nt], acc[mt][nt], 0, 0, 0);
    }

#pragma unroll
    for (int nt = 0; nt < 4; nt++) {
        const int col = col0 + wc * 64 + nt * 16 + lrow;
#pragma unroll
        for (int mt = 0; mt < 4; mt++) {
            f32x4 a = acc[mt][nt];
#pragma unroll
            for (int r = 0; r < 4; r++) {
                const int row = row0 + wr * 64 + mt * 16 + quad * 4 + r;
                C[(size_t)row * 256 + col] = a[r];
            }
        }
    }
}

// ---------------------------------------------------------------------------
// Merged value+query GEMM: N=640, BT = [w_valueT | w_offT | w_attnT].
// col < 256  -> val (bf16, stride 256);  col >= 256 -> qout (fp32, stride 384).
// ---------------------------------------------------------------------------
__global__ __launch_bounds__(256) void qv_gemm(
        const float* __restrict__ src, const float* __restrict__ pos,
        const unsigned short* __restrict__ BT, const float* __restrict__ bias,
        unsigned short* __restrict__ val, float* __restrict__ qout) {
    __shared__ unsigned short Ash[128][40];
    __shared__ unsigned short Bsh[128][40];

    const int t = threadIdx.x;
    const int wave = t >> 6, lane = t & 63;
    const int wr = wave >> 1, wc = wave & 1;
    const int lrow = lane & 15, quad = lane >> 4;
    const int row0 = blockIdx.x * 128;
    const int col0 = blockIdx.y * 128;
    const bool addp = (col0 >= 256);

    const int srow = t >> 1;
    const int cb = (t & 1) * 16;

    f32x4 acc[4][4];
#pragma unroll
    for (int i = 0; i < 4; i++)
#pragma unroll
        for (int j = 0; j < 4; j++) acc[i][j] = (f32x4){0.f, 0.f, 0.f, 0.f};

    for (int kb = 0; kb < 256; kb += 32) {
        __syncthreads();
        {
            const float* ap = src + (size_t)(row0 + srow) * 256 + kb + cb;
            float4 f0 = *(const float4*)(ap + 0);
            float4 f1 = *(const float4*)(ap + 4);
            float4 f2 = *(const float4*)(ap + 8);
            float4 f3 = *(const float4*)(ap + 12);
            if (addp) {
                const float* pp = pos + (size_t)(row0 + srow) * 256 + kb + cb;
                float4 p0 = *(const float4*)(pp + 0);
                float4 p1 = *(const float4*)(pp + 4);
                float4 p2 = *(const float4*)(pp + 8);
                float4 p3 = *(const float4*)(pp + 12);
                f0.x += p0.x; f0.y += p0.y; f0.z += p0.z; f0.w += p0.w;
                f1.x += p1.x; f1.y += p1.y; f1.z += p1.z; f1.w += p1.w;
                f2.x += p2.x; f2.y += p2.y; f2.z += p2.z; f2.w += p2.w;
                f3.x += p3.x; f3.y += p3.y; f3.z += p3.z; f3.w += p3.w;
            }
            uint4 u0 = make_uint4(pack2(f0.x, f0.y), pack2(f0.z, f0.w),
                                  pack2(f1.x, f1.y), pack2(f1.z, f1.w));
            uint4 u1 = make_uint4(pack2(f2.x, f2.y), pack2(f2.z, f2.w),
                                  pack2(f3.x, f3.y), pack2(f3.z, f3.w));
            *(uint4*)&Ash[srow][cb + 0] = u0;
            *(uint4*)&Ash[srow][cb + 8] = u1;
        }
        {
            const unsigned short* bp = BT + (size_t)(col0 + srow) * 256 + kb + cb;
            *(uint4*)&Bsh[srow][cb + 0] = *(const uint4*)(bp + 0);
            *(uint4*)&Bsh[srow][cb + 8] = *(const uint4*)(bp + 8);
        }
        __syncthreads();

        short8 af[4], bfr[4];
#pragma unroll
        for (int mt = 0; mt < 4; mt++)
            af[mt] = *(const short8*)&Ash[wr * 64 + mt * 16 + lrow][quad * 8];
#pragma unroll
        for (int nt = 0; nt < 4; nt++)
            bfr[nt] = *(const short8*)&Bsh[wc * 64 + nt * 16 + lrow][quad * 8];
#pragma unroll
        for (int mt = 0; mt < 4; mt++)
#pragma unroll
            for (int nt = 0; nt < 4; nt++)
                acc[mt][nt] = __builtin_amdgcn_mfma_f32_16x16x32_bf16(
                    af[mt], bfr[nt], acc[mt][nt], 0, 0, 0);
    }

#pragma unroll
    for (int nt = 0; nt < 4; nt++) {
        const int col = col0 + wc * 64 + nt * 16 + lrow;
        const float bv = bias[col];
#pragma unroll
        for (int mt = 0; mt < 4; mt++) {
            f32x4 a = acc[mt][nt];
#pragma unroll
            for (int r = 0; r < 4; r++) {
                const int row = row0 + wr * 64 + mt * 16 + quad * 4 + r;
                float v = a[r] + bv;
                if (col < 256)
                    val[(size_t)row * 256 + col] = f2bf(v);
                else
                    qout[(size_t)row * 384 + (col - 256)] = v;
            }
        }
    }
}

// ---------------------------------------------------------------------------
// Two-phase sampler (phase1: softmax+corner precompute -> LDS; phase2: gather)
// ---------------------------------------------------------------------------
__global__ void sampler(const unsigned short* __restrict__ val, const float* __restrict__ qout,
                        unsigned short* __restrict__ out) {
    __shared__ __align__(16) int   sIdx[128][4];
    __shared__ __align__(16) float sW[128][4];
    const int bq = blockIdx.x;
    const int b = bq / LEN, q = bq % LEN;
    const int t = threadIdx.x;

    if (t < 128) {
        const int h = t >> 4, p = t & 15;
        const int l = p >> 2;

        float refx, refy;
        if (q < 4096) {
            int rq = q >> 6, cq = q & 63;
            refx = (cq + 0.5f) * (1.0f / 64.0f);
            refy = (rq + 0.5f) * (1.0f / 64.0f);
        } else if (q < 5120) {
            int qq = q - 4096;
            int rq = qq >> 5, cq = qq & 31;
            refx = (cq + 0.5f) * (1.0f / 32.0f);
            refy = (rq + 0.5f) * (1.0f / 32.0f);
        } else if (q < 5376) {
            int qq = q - 5120;
            int rq = qq >> 4, cq = qq & 15;
            refx = (cq + 0.5f) * (1.0f / 16.0f);
            refy = (rq + 0.5f) * (1.0f / 16.0f);
        } else {
            int qq = q - 5376;
            int rq = qq >> 3, cq = qq & 7;
            refx = (cq + 0.5f) * (1.0f / 8.0f);
            refy = (rq + 0.5f) * (1.0f / 8.0f);
        }

        float lv = qout[(size_t)bq * 384 + 256 + t];
        float mx = lv;
#pragma unroll
        for (int o = 1; o < 16; o <<= 1) mx = fmaxf(mx, __shfl_xor(mx, o, 16));
        float e = expf(lv - mx);
        float s = e;
#pragma unroll
        for (int o = 1; o < 16; o <<= 1) s += __shfl_xor(s, o, 16);
        const float aw = e / s;

        const float ox = qout[(size_t)bq * 384 + h * 32 + p * 2 + 0];
        const float oy = qout[(size_t)bq * 384 + h * 32 + p * 2 + 1];

        const int LST[4] = {0, 4096, 5120, 5376};
        const int WW = 64 >> l;
        const float rw = 1.0f / (float)WW;

        float x = (refx + ox * rw) * (float)WW - 0.5f;
        float y = (refy + oy * rw) * (float)WW - 0.5f;
        float x0f = floorf(x), y0f = floorf(y);
        float dx = x - x0f, dy = y - y0f;
        int x0 = (int)x0f, y0 = (int)y0f;

        const int base = (b * LEN + LST[l]) * 256 + h * 32;
        int4 iv; float4 wv;
        {
            int xs[2] = {x0, x0 + 1}, ys[2] = {y0, y0 + 1};
            float wx[2] = {1.f - dx, dx}, wy[2] = {1.f - dy, dy};
            int ic[4]; float wc4[4];
#pragma unroll
            for (int cy = 0; cy < 2; cy++)
#pragma unroll
                for (int cx = 0; cx < 2; cx++) {
                    int xi = xs[cx], yi = ys[cy];
                    bool vld = (xi >= 0) && (xi < WW) && (yi >= 0) && (yi < WW);
                    int xc = min(max(xi, 0), WW - 1);
                    int yc = min(max(yi, 0), WW - 1);
                    ic[cy * 2 + cx] = base + (yc * WW + xc) * 256;
                    wc4[cy * 2 + cx] = vld ? wx[cx] * wy[cy] * aw : 0.f;
                }
            iv = make_int4(ic[0], ic[1], ic[2], ic[3]);
            wv = make_float4(wc4[0], wc4[1], wc4[2], wc4[3]);
        }
        *(int4*)&sIdx[t][0] = iv;
        *(float4*)&sW[t][0] = wv;
    }
    __syncthreads();

    const int h = t >> 5, d = t & 31;
    const unsigned short* vald = val + d;
    float acc = 0.f;
#pragma unroll 4
    for (int p = 0; p < 16; p++) {
        const int r = h * 16 + p;
        int4 iv = *(const int4*)&sIdx[r][0];
        float4 wv = *(const float4*)&sW[r][0];
        acc += bf2f(vald[iv.x]) * wv.x;
        acc += bf2f(vald[iv.y]) * wv.y;
        acc += bf2f(vald[iv.z]) * wv.z;
        acc += bf2f(vald[iv.w]) * wv.w;
    }
    out[(size_t)bq * D + h * HD + d] = f2bf(acc);
}

// ---------------------------------------------------------------------------
// out = LayerNorm(p0 + p1 + bias + rsd) * g + be  (one row per block)
// Folds the split-K partial reduce + bias into the LN pass.
// ---------------------------------------------------------------------------
__global__ void add_ln2(const float* __restrict__ p0, const float* __restrict__ p1,
                        const float* __restrict__ bias, const float* __restrict__ rsd,
                        const float* __restrict__ g, const float* __restrict__ be,
                        float* __restrict__ out) {
    __shared__ float r1[4], r2[4];
    const int row = blockIdx.x, t = threadIdx.x;
    const size_t i = (size_t)row * D + t;
    const float v = p0[i] + p1[i] + bias[t] + rsd[i];
    float s1 = v, s2 = v * v;
#pragma unroll
    for (int o = 32; o > 0; o >>= 1) {
        s1 += __shfl_down(s1, o, 64);
        s2 += __shfl_down(s2, o, 64);
    }
    if ((t & 63) == 0) { r1[t >> 6] = s1; r2[t >> 6] = s2; }
    __syncthreads();
    float su = r1[0] + r1[1] + r1[2] + r1[3];
    float sq = r2[0] + r2[1] + r2[2] + r2[3];
    float mean = su * (1.0f / D);
    float var = fmaxf(sq * (1.0f / D) - mean * mean, 0.f);
    out[i] = (v - mean) * rsqrtf(var + 1e-5f) * g[t] + be[t];
}

// ---------------------------------------------------------------------------
extern "C" void kernel_launch(void* const* d_in, const int* in_sizes, int n_in,
                              void* d_out, int out_size, void* d_ws, size_t ws_size,
                              hipStream_t stream) {
    const float* src     = (const float*)d_in[0];
    const float* pos     = (const float*)d_in[1];
    const float* w_value = (const float*)d_in[4];
    const float* b_value = (const float*)d_in[5];
    const float* w_off   = (const float*)d_in[6];
    const float* b_off   = (const float*)d_in[7];
    const float* w_attn  = (const float*)d_in[8];
    const float* b_attn  = (const float*)d_in[9];
    const float* w_out   = (const float*)d_in[10];
    const float* b_out   = (const float*)d_in[11];
    const float* w1      = (const float*)d_in[12];
    const float* b1      = (const float*)d_in[13];
    const float* w2      = (const float*)d_in[14];
    const float* b2      = (const float*)d_in[15];
    const float* g1      = (const float*)d_in[16];
    const float* be1     = (const float*)d_in[17];
    const float* g2      = (const float*)d_in[18];
    const float* be2     = (const float*)d_in[19];
    float* out = (float*)d_out;

    // ---- workspace layout (~108 MB; ws_size = 256 MiB per harness poison) ----
    size_t off = 0;
    auto alloc = [&](size_t bytes) -> char* {
        char* p = (char*)d_ws + off;
        off += (bytes + 255) & ~(size_t)255;
        return p;
    };
    unsigned short* wqvT = (unsigned short*)alloc((size_t)640 * 256 * 2);
    unsigned short* woT  = (unsigned short*)alloc(256 * 256 * 2);
    unsigned short* w1T  = (unsigned short*)alloc((size_t)2048 * 256 * 2);
    unsigned short* w2T  = (unsigned short*)alloc((size_t)256 * 2048 * 2);
    float* bqv           = (float*)alloc(640 * 4);

    float* qout          = (float*)alloc((size_t)MROWS * 384 * 4);   // 16.71 MB
    unsigned short* val  = (unsigned short*)alloc((size_t)MROWS * 256 * 2);
    unsigned short* attn = (unsigned short*)alloc((size_t)MROWS * 256 * 2);
    unsigned short* hb   = (unsigned short*)alloc((size_t)MROWS * 2048 * 2);  // 44.6 MB
    float* xbuf          = (float*)alloc((size_t)MROWS * 256 * 4);
    float* part          = (float*)alloc((size_t)2 * MROWS * 256 * 4);        // 22.3 MB

    // ---- weight prep (single launch) ----
    prep<<<1249, 256, 0, stream>>>(w_value, w_off, w_attn, w_out, w1, w2,
                                   b_value, b_off, b_attn, wqvT, woT, w1T, w2T, bqv);

    // ---- attention ----
    qv_gemm<<<dim3(85, 5), 256, 0, stream>>>(src, pos, wqvT, bqv, val, qout);
    sampler<<<MROWS, 256, 0, stream>>>(val, qout, attn);
    // proj split-K (K=256 -> 2 x 128): part[z] = attn[:, z*128:] @ woT^T
    splitk_gemm<<<dim3(85, 2, 2), 256, 0, stream>>>(attn, woT, part, 128, 256, 256);
    // x = LN(part0 + part1 + b_out + src) -> xbuf
    add_ln2<<<MROWS, 256, 0, stream>>>(part, part + (size_t)MROWS * 256, b_out, src,
                                       g1, be1, xbuf);

    // ---- FFN ----
    // hb = relu(xbuf @ w1 + b1)  (full N=2048, 1360 blocks)
    mfma_gemm<true, true, true><<<dim3(85, 16), 256, 0, stream>>>(
        xbuf, w1T, b1, hb, 2048, 256, 256, 256);
    // ffn2 split-K (K=2048 -> 2 x 1024): part[z] = hb[:, z*1024:] @ w2T^T
    splitk_gemm<<<dim3(85, 2, 2), 256, 0, stream>>>(hb, w2T, part, 1024, 2048, 2048);
    // out = LN(part0 + part1 + b2 + xbuf)
    add_ln2<<<MROWS, 256, 0, stream>>>(part, part + (size_t)MROWS * 256, b2, xbuf,
                                       g2, be2, out);
}

// Round 7
// 242.505 us; speedup vs baseline: 3.6186x; 1.0767x over previous
//
#include <hip/hip_runtime.h>
#include <math.h>

#define D 256
#define NH 8
#define NL 4
#define NP 4
#define DFF 2048
#define HD 32
#define BB 2
#define LEN 5440
#define MROWS (BB * LEN)   // 10880 = 85 * 128 exactly

typedef __attribute__((ext_vector_type(8))) short short8;
typedef __attribute__((ext_vector_type(4))) float f32x4;
typedef unsigned int uint32;

__device__ __forceinline__ unsigned short f2bf(float f) {
    uint32 u = __float_as_uint(f);
    u += 0x7FFF + ((u >> 16) & 1);           // round-to-nearest-even
    return (unsigned short)(u >> 16);
}
__device__ __forceinline__ float bf2f(unsigned short h) {
    return __uint_as_float(((uint32)h) << 16);
}
__device__ __forceinline__ uint32 pack2(float a, float b) {
    return (uint32)f2bf(a) | ((uint32)f2bf(b) << 16);
}

// XCD-affinity swizzle: 85 row-tiles x ncols col-tiles, flat block id ->
// (row, col) s.t. all cols of a row share id%8 (= XCD on round-robin HW).
// Groups of 8 rows x ncols; within a group idx%8 = local row.
__device__ __forceinline__ void swz85(int b, int ncols, int& row, int& col) {
    const int gsz = ncols << 3;      // 8 rows worth
    const int full = 10 * gsz;       // 80 rows in full groups
    if (b < full) {
        const int g = b / gsz, idx = b - g * gsz;
        row = (g << 3) + (idx & 7);
        col = idx >> 3;
    } else {                         // last 5 rows (affinity relaxed)
        const int idx = b - full;
        row = 80 + idx % 5;
        col = idx / 5;
    }
}

// ---------------------------------------------------------------------------
// prep: all weight transposes (fp32 [KxN] -> bf16 [NxK]) + bias concat.
// ---------------------------------------------------------------------------
__global__ void prep(const float* __restrict__ w_value, const float* __restrict__ w_off,
                     const float* __restrict__ w_attn, const float* __restrict__ w_out,
                     const float* __restrict__ w1, const float* __restrict__ w2,
                     const float* __restrict__ b_value, const float* __restrict__ b_off,
                     const float* __restrict__ b_attn,
                     unsigned short* __restrict__ wqvT, unsigned short* __restrict__ woT,
                     unsigned short* __restrict__ w1T, unsigned short* __restrict__ w2T,
                     float* __restrict__ bqv) {
    const int blk = blockIdx.x;
    if (blk >= 1248) {
        for (int i = threadIdx.x; i < 640; i += 256)
            bqv[i] = (i < 256) ? b_value[i] : (i < 512 ? b_off[i - 256] : b_attn[i - 512]);
        return;
    }
    const float* W; unsigned short* WT; int K, N, tid;
    if (blk < 64)       { W = w_value; WT = wqvT;             K = 256;  N = 256;  tid = blk; }
    else if (blk < 128) { W = w_off;   WT = wqvT + 256 * 256; K = 256;  N = 256;  tid = blk - 64; }
    else if (blk < 160) { W = w_attn;  WT = wqvT + 512 * 256; K = 256;  N = 128;  tid = blk - 128; }
    else if (blk < 224) { W = w_out;   WT = woT;              K = 256;  N = 256;  tid = blk - 160; }
    else if (blk < 736) { W = w1;      WT = w1T;              K = 256;  N = 2048; tid = blk - 224; }
    else                { W = w2;      WT = w2T;              K = 2048; N = 256;  tid = blk - 736; }
    const int ntx = N >> 5;
    const int nb = (tid % ntx) * 32, kb = (tid / ntx) * 32;

    __shared__ float tile[32][33];
    const int tx = threadIdx.x & 31, ty = threadIdx.x >> 5;
#pragma unroll
    for (int i = 0; i < 32; i += 8)
        tile[ty + i][tx] = W[(size_t)(kb + ty + i) * N + nb + tx];
    __syncthreads();
#pragma unroll
    for (int i = 0; i < 32; i += 8)
        WT[(size_t)(nb + ty + i) * K + kb + tx] = f2bf(tile[tx][ty + i]);
}

// ---------------------------------------------------------------------------
// ffn1 GEMM: C = relu(A @ BT^T + bias) -> bf16. A bf16. 128x128 tile,
// flat grid with XCD-affinity swizzle (ncols = N/128).
// ---------------------------------------------------------------------------
__global__ __launch_bounds__(256) void ffn1_gemm(
        const unsigned short* __restrict__ A,
        const unsigned short* __restrict__ BT, const float* __restrict__ bias,
        unsigned short* __restrict__ Cv, int N, int K, int lda, int ldb) {
    __shared__ unsigned short Ash[128][40];
    __shared__ unsigned short Bsh[128][40];

    int rowt, colt;
    swz85(blockIdx.x, N >> 7, rowt, colt);
    const int row0 = rowt * 128, col0 = colt * 128;

    const int t = threadIdx.x;
    const int wave = t >> 6, lane = t & 63;
    const int wr = wave >> 1, wc = wave & 1;
    const int lrow = lane & 15, quad = lane >> 4;
    const int srow = t >> 1;
    const int cb = (t & 1) * 16;

    f32x4 acc[4][4];
#pragma unroll
    for (int i = 0; i < 4; i++)
#pragma unroll
        for (int j = 0; j < 4; j++) acc[i][j] = (f32x4){0.f, 0.f, 0.f, 0.f};

    for (int kb = 0; kb < K; kb += 32) {
        __syncthreads();
        {
            const unsigned short* ap = A + (size_t)(row0 + srow) * lda + kb + cb;
            *(uint4*)&Ash[srow][cb + 0] = *(const uint4*)(ap + 0);
            *(uint4*)&Ash[srow][cb + 8] = *(const uint4*)(ap + 8);
        }
        {
            const unsigned short* bp = BT + (size_t)(col0 + srow) * ldb + kb + cb;
            *(uint4*)&Bsh[srow][cb + 0] = *(const uint4*)(bp + 0);
            *(uint4*)&Bsh[srow][cb + 8] = *(const uint4*)(bp + 8);
        }
        __syncthreads();

        short8 af[4], bfr[4];
#pragma unroll
        for (int mt = 0; mt < 4; mt++)
            af[mt] = *(const short8*)&Ash[wr * 64 + mt * 16 + lrow][quad * 8];
#pragma unroll
        for (int nt = 0; nt < 4; nt++)
            bfr[nt] = *(const short8*)&Bsh[wc * 64 + nt * 16 + lrow][quad * 8];
#pragma unroll
        for (int mt = 0; mt < 4; mt++)
#pragma unroll
            for (int nt = 0; nt < 4; nt++)
                acc[mt][nt] = __builtin_amdgcn_mfma_f32_16x16x32_bf16(
                    af[mt], bfr[nt], acc[mt][nt], 0, 0, 0);
    }

#pragma unroll
    for (int nt = 0; nt < 4; nt++) {
        const int col = col0 + wc * 64 + nt * 16 + lrow;
        const float bv = bias[col];
#pragma unroll
        for (int mt = 0; mt < 4; mt++) {
            f32x4 a = acc[mt][nt];
#pragma unroll
            for (int r = 0; r < 4; r++) {
                const int row = row0 + wr * 64 + mt * 16 + quad * 4 + r;
                Cv[(size_t)row * N + col] = f2bf(fmaxf(a[r] + bv, 0.f));
            }
        }
    }
}

// ---------------------------------------------------------------------------
// Split-K GEMM (N=256): flat grid 340 = 85 rows x {2 cols x 2 kchunks},
// XCD-affinity swizzle. partial[z] = A[:, z*KC:] @ BT[:, z*KC:]^T (fp32).
// ---------------------------------------------------------------------------
__global__ __launch_bounds__(256) void splitk_gemm(
        const unsigned short* __restrict__ A, const unsigned short* __restrict__ BT,
        float* __restrict__ part, int KC, int lda, int ldb) {
    __shared__ unsigned short Ash[128][40];
    __shared__ unsigned short Bsh[128][40];

    int rowt, cc;
    swz85(blockIdx.x, 4, rowt, cc);
    const int row0 = rowt * 128;
    const int col0 = (cc & 1) * 128;
    const int z = cc >> 1;
    const int koff = z * KC;
    float* __restrict__ C = part + (size_t)z * MROWS * 256;

    const int t = threadIdx.x;
    const int wave = t >> 6, lane = t & 63;
    const int wr = wave >> 1, wc = wave & 1;
    const int lrow = lane & 15, quad = lane >> 4;
    const int srow = t >> 1;
    const int cb = (t & 1) * 16;

    f32x4 acc[4][4];
#pragma unroll
    for (int i = 0; i < 4; i++)
#pragma unroll
        for (int j = 0; j < 4; j++) acc[i][j] = (f32x4){0.f, 0.f, 0.f, 0.f};

    for (int kb = 0; kb < KC; kb += 32) {
        __syncthreads();
        {
            const unsigned short* ap = A + (size_t)(row0 + srow) * lda + koff + kb + cb;
            *(uint4*)&Ash[srow][cb + 0] = *(const uint4*)(ap + 0);
            *(uint4*)&Ash[srow][cb + 8] = *(const uint4*)(ap + 8);
        }
        {
            const unsigned short* bp = BT + (size_t)(col0 + srow) * ldb + koff + kb + cb;
            *(uint4*)&Bsh[srow][cb + 0] = *(const uint4*)(bp + 0);
            *(uint4*)&Bsh[srow][cb + 8] = *(const uint4*)(bp + 8);
        }
        __syncthreads();

        short8 af[4], bfr[4];
#pragma unroll
        for (int mt = 0; mt < 4; mt++)
            af[mt] = *(const short8*)&Ash[wr * 64 + mt * 16 + lrow][quad * 8];
#pragma unroll
        for (int nt = 0; nt < 4; nt++)
            bfr[nt] = *(const short8*)&Bsh[wc * 64 + nt * 16 + lrow][quad * 8];
#pragma unroll
        for (int mt = 0; mt < 4; mt++)
#pragma unroll
            for (int nt = 0; nt < 4; nt++)
                acc[mt][nt] = __builtin_amdgcn_mfma_f32_16x16x32_bf16(
                    af[mt], bfr[nt], acc[mt][nt], 0, 0, 0);
    }

#pragma unroll
    for (int nt = 0; nt < 4; nt++) {
        const int col = col0 + wc * 64 + nt * 16 + lrow;
#pragma unroll
        for (int mt = 0; mt < 4; mt++) {
            f32x4 a = acc[mt][nt];
#pragma unroll
            for (int r = 0; r < 4; r++) {
                const int row = row0 + wr * 64 + mt * 16 + quad * 4 + r;
                C[(size_t)row * 256 + col] = a[r];
            }
        }
    }
}

// ---------------------------------------------------------------------------
// Merged value+query GEMM: flat grid 425 = 85 rows x 5 cols, swizzled.
// col < 256 -> val (bf16); col >= 256 -> qout (fp32, stride 384).
// ---------------------------------------------------------------------------
__global__ __launch_bounds__(256) void qv_gemm(
        const float* __restrict__ src, const float* __restrict__ pos,
        const unsigned short* __restrict__ BT, const float* __restrict__ bias,
        unsigned short* __restrict__ val, float* __restrict__ qout) {
    __shared__ unsigned short Ash[128][40];
    __shared__ unsigned short Bsh[128][40];

    int rowt, colt;
    swz85(blockIdx.x, 5, rowt, colt);
    const int row0 = rowt * 128, col0 = colt * 128;
    const bool addp = (col0 >= 256);

    const int t = threadIdx.x;
    const int wave = t >> 6, lane = t & 63;
    const int wr = wave >> 1, wc = wave & 1;
    const int lrow = lane & 15, quad = lane >> 4;
    const int srow = t >> 1;
    const int cb = (t & 1) * 16;

    f32x4 acc[4][4];
#pragma unroll
    for (int i = 0; i < 4; i++)
#pragma unroll
        for (int j = 0; j < 4; j++) acc[i][j] = (f32x4){0.f, 0.f, 0.f, 0.f};

    for (int kb = 0; kb < 256; kb += 32) {
        __syncthreads();
        {
            const float* ap = src + (size_t)(row0 + srow) * 256 + kb + cb;
            float4 f0 = *(const float4*)(ap + 0);
            float4 f1 = *(const float4*)(ap + 4);
            float4 f2 = *(const float4*)(ap + 8);
            float4 f3 = *(const float4*)(ap + 12);
            if (addp) {
                const float* pp = pos + (size_t)(row0 + srow) * 256 + kb + cb;
                float4 p0 = *(const float4*)(pp + 0);
                float4 p1 = *(const float4*)(pp + 4);
                float4 p2 = *(const float4*)(pp + 8);
                float4 p3 = *(const float4*)(pp + 12);
                f0.x += p0.x; f0.y += p0.y; f0.z += p0.z; f0.w += p0.w;
                f1.x += p1.x; f1.y += p1.y; f1.z += p1.z; f1.w += p1.w;
                f2.x += p2.x; f2.y += p2.y; f2.z += p2.z; f2.w += p2.w;
                f3.x += p3.x; f3.y += p3.y; f3.z += p3.z; f3.w += p3.w;
            }
            uint4 u0 = make_uint4(pack2(f0.x, f0.y), pack2(f0.z, f0.w),
                                  pack2(f1.x, f1.y), pack2(f1.z, f1.w));
            uint4 u1 = make_uint4(pack2(f2.x, f2.y), pack2(f2.z, f2.w),
                                  pack2(f3.x, f3.y), pack2(f3.z, f3.w));
            *(uint4*)&Ash[srow][cb + 0] = u0;
            *(uint4*)&Ash[srow][cb + 8] = u1;
        }
        {
            const unsigned short* bp = BT + (size_t)(col0 + srow) * 256 + kb + cb;
            *(uint4*)&Bsh[srow][cb + 0] = *(const uint4*)(bp + 0);
            *(uint4*)&Bsh[srow][cb + 8] = *(const uint4*)(bp + 8);
        }
        __syncthreads();

        short8 af[4], bfr[4];
#pragma unroll
        for (int mt = 0; mt < 4; mt++)
            af[mt] = *(const short8*)&Ash[wr * 64 + mt * 16 + lrow][quad * 8];
#pragma unroll
        for (int nt = 0; nt < 4; nt++)
            bfr[nt] = *(const short8*)&Bsh[wc * 64 + nt * 16 + lrow][quad * 8];
#pragma unroll
        for (int mt = 0; mt < 4; mt++)
#pragma unroll
            for (int nt = 0; nt < 4; nt++)
                acc[mt][nt] = __builtin_amdgcn_mfma_f32_16x16x32_bf16(
                    af[mt], bfr[nt], acc[mt][nt], 0, 0, 0);
    }

#pragma unroll
    for (int nt = 0; nt < 4; nt++) {
        const int col = col0 + wc * 64 + nt * 16 + lrow;
        const float bv = bias[col];
#pragma unroll
        for (int mt = 0; mt < 4; mt++) {
            f32x4 a = acc[mt][nt];
#pragma unroll
            for (int r = 0; r < 4; r++) {
                const int row = row0 + wr * 64 + mt * 16 + quad * 4 + r;
                float v = a[r] + bv;
                if (col < 256)
                    val[(size_t)row * 256 + col] = f2bf(v);
                else
                    qout[(size_t)row * 384 + (col - 256)] = v;
            }
        }
    }
}

// ---------------------------------------------------------------------------
// Two-phase sampler (phase1: softmax+corner precompute -> LDS; phase2: gather)
// ---------------------------------------------------------------------------
__global__ void sampler(const unsigned short* __restrict__ val, const float* __restrict__ qout,
                        unsigned short* __restrict__ out) {
    __shared__ __align__(16) int   sIdx[128][4];
    __shared__ __align__(16) float sW[128][4];
    const int bq = blockIdx.x;
    const int b = bq / LEN, q = bq % LEN;
    const int t = threadIdx.x;

    if (t < 128) {
        const int h = t >> 4, p = t & 15;
        const int l = p >> 2;

        float refx, refy;
        if (q < 4096) {
            int rq = q >> 6, cq = q & 63;
            refx = (cq + 0.5f) * (1.0f / 64.0f);
            refy = (rq + 0.5f) * (1.0f / 64.0f);
        } else if (q < 5120) {
            int qq = q - 4096;
            int rq = qq >> 5, cq = qq & 31;
            refx = (cq + 0.5f) * (1.0f / 32.0f);
            refy = (rq + 0.5f) * (1.0f / 32.0f);
        } else if (q < 5376) {
            int qq = q - 5120;
            int rq = qq >> 4, cq = qq & 15;
            refx = (cq + 0.5f) * (1.0f / 16.0f);
            refy = (rq + 0.5f) * (1.0f / 16.0f);
        } else {
            int qq = q - 5376;
            int rq = qq >> 3, cq = qq & 7;
            refx = (cq + 0.5f) * (1.0f / 8.0f);
            refy = (rq + 0.5f) * (1.0f / 8.0f);
        }

        float lv = qout[(size_t)bq * 384 + 256 + t];
        float mx = lv;
#pragma unroll
        for (int o = 1; o < 16; o <<= 1) mx = fmaxf(mx, __shfl_xor(mx, o, 16));
        float e = expf(lv - mx);
        float s = e;
#pragma unroll
        for (int o = 1; o < 16; o <<= 1) s += __shfl_xor(s, o, 16);
        const float aw = e / s;

        const float ox = qout[(size_t)bq * 384 + h * 32 + p * 2 + 0];
        const float oy = qout[(size_t)bq * 384 + h * 32 + p * 2 + 1];

        const int LST[4] = {0, 4096, 5120, 5376};
        const int WW = 64 >> l;
        const float rw = 1.0f / (float)WW;

        float x = (refx + ox * rw) * (float)WW - 0.5f;
        float y = (refy + oy * rw) * (float)WW - 0.5f;
        float x0f = floorf(x), y0f = floorf(y);
        float dx = x - x0f, dy = y - y0f;
        int x0 = (int)x0f, y0 = (int)y0f;

        const int base = (b * LEN + LST[l]) * 256 + h * 32;
        int4 iv; float4 wv;
        {
            int xs[2] = {x0, x0 + 1}, ys[2] = {y0, y0 + 1};
            float wx[2] = {1.f - dx, dx}, wy[2] = {1.f - dy, dy};
            int ic[4]; float wc4[4];
#pragma unroll
            for (int cy = 0; cy < 2; cy++)
#pragma unroll
                for (int cx = 0; cx < 2; cx++) {
                    int xi = xs[cx], yi = ys[cy];
                    bool vld = (xi >= 0) && (xi < WW) && (yi >= 0) && (yi < WW);
                    int xc = min(max(xi, 0), WW - 1);
                    int yc = min(max(yi, 0), WW - 1);
                    ic[cy * 2 + cx] = base + (yc * WW + xc) * 256;
                    wc4[cy * 2 + cx] = vld ? wx[cx] * wy[cy] * aw : 0.f;
                }
            iv = make_int4(ic[0], ic[1], ic[2], ic[3]);
            wv = make_float4(wc4[0], wc4[1], wc4[2], wc4[3]);
        }
        *(int4*)&sIdx[t][0] = iv;
        *(float4*)&sW[t][0] = wv;
    }
    __syncthreads();

    const int h = t >> 5, d = t & 31;
    const unsigned short* vald = val + d;
    float acc = 0.f;
#pragma unroll 4
    for (int p = 0; p < 16; p++) {
        const int r = h * 16 + p;
        int4 iv = *(const int4*)&sIdx[r][0];
        float4 wv = *(const float4*)&sW[r][0];
        acc += bf2f(vald[iv.x]) * wv.x;
        acc += bf2f(vald[iv.y]) * wv.y;
        acc += bf2f(vald[iv.z]) * wv.z;
        acc += bf2f(vald[iv.w]) * wv.w;
    }
    out[(size_t)bq * D + h * HD + d] = f2bf(acc);
}

// ---------------------------------------------------------------------------
// out = LayerNorm(p0 + p1 + bias + rsd) * g + be  (one row per block)
// Optionally also writes bf16 copy (out16) for downstream bf16 GEMM A.
// ---------------------------------------------------------------------------
__global__ void add_ln2(const float* __restrict__ p0, const float* __restrict__ p1,
                        const float* __restrict__ bias, const float* __restrict__ rsd,
                        const float* __restrict__ g, const float* __restrict__ be,
                        float* __restrict__ out, unsigned short* __restrict__ out16) {
    __shared__ float r1[4], r2[4];
    const int row = blockIdx.x, t = threadIdx.x;
    const size_t i = (size_t)row * D + t;
    const float v = p0[i] + p1[i] + bias[t] + rsd[i];
    float s1 = v, s2 = v * v;
#pragma unroll
    for (int o = 32; o > 0; o >>= 1) {
        s1 += __shfl_down(s1, o, 64);
        s2 += __shfl_down(s2, o, 64);
    }
    if ((t & 63) == 0) { r1[t >> 6] = s1; r2[t >> 6] = s2; }
    __syncthreads();
    float su = r1[0] + r1[1] + r1[2] + r1[3];
    float sq = r2[0] + r2[1] + r2[2] + r2[3];
    float mean = su * (1.0f / D);
    float var = fmaxf(sq * (1.0f / D) - mean * mean, 0.f);
    const float o = (v - mean) * rsqrtf(var + 1e-5f) * g[t] + be[t];
    out[i] = o;
    if (out16) out16[i] = f2bf(o);
}

// ---------------------------------------------------------------------------
extern "C" void kernel_launch(void* const* d_in, const int* in_sizes, int n_in,
                              void* d_out, int out_size, void* d_ws, size_t ws_size,
                              hipStream_t stream) {
    const float* src     = (const float*)d_in[0];
    const float* pos     = (const float*)d_in[1];
    const float* w_value = (const float*)d_in[4];
    const float* b_value = (const float*)d_in[5];
    const float* w_off   = (const float*)d_in[6];
    const float* b_off   = (const float*)d_in[7];
    const float* w_attn  = (const float*)d_in[8];
    const float* b_attn  = (const float*)d_in[9];
    const float* w_out   = (const float*)d_in[10];
    const float* b_out   = (const float*)d_in[11];
    const float* w1      = (const float*)d_in[12];
    const float* b1      = (const float*)d_in[13];
    const float* w2      = (const float*)d_in[14];
    const float* b2      = (const float*)d_in[15];
    const float* g1      = (const float*)d_in[16];
    const float* be1     = (const float*)d_in[17];
    const float* g2      = (const float*)d_in[18];
    const float* be2     = (const float*)d_in[19];
    float* out = (float*)d_out;

    // ---- workspace layout (~114 MB of the 256 MiB ws) ----
    size_t off = 0;
    auto alloc = [&](size_t bytes) -> char* {
        char* p = (char*)d_ws + off;
        off += (bytes + 255) & ~(size_t)255;
        return p;
    };
    unsigned short* wqvT = (unsigned short*)alloc((size_t)640 * 256 * 2);
    unsigned short* woT  = (unsigned short*)alloc(256 * 256 * 2);
    unsigned short* w1T  = (unsigned short*)alloc((size_t)2048 * 256 * 2);
    unsigned short* w2T  = (unsigned short*)alloc((size_t)256 * 2048 * 2);
    float* bqv           = (float*)alloc(640 * 4);

    float* qout          = (float*)alloc((size_t)MROWS * 384 * 4);   // 16.71 MB
    unsigned short* val  = (unsigned short*)alloc((size_t)MROWS * 256 * 2);
    unsigned short* attn = (unsigned short*)alloc((size_t)MROWS * 256 * 2);
    unsigned short* hb   = (unsigned short*)alloc((size_t)MROWS * 2048 * 2);  // 44.6 MB
    float* xbuf          = (float*)alloc((size_t)MROWS * 256 * 4);
    unsigned short* xb16 = (unsigned short*)alloc((size_t)MROWS * 256 * 2);
    float* part          = (float*)alloc((size_t)2 * MROWS * 256 * 4);        // 22.3 MB

    // ---- weight prep (single launch) ----
    prep<<<1249, 256, 0, stream>>>(w_value, w_off, w_attn, w_out, w1, w2,
                                   b_value, b_off, b_attn, wqvT, woT, w1T, w2T, bqv);

    // ---- attention ----
    qv_gemm<<<425, 256, 0, stream>>>(src, pos, wqvT, bqv, val, qout);
    sampler<<<MROWS, 256, 0, stream>>>(val, qout, attn);
    // proj split-K (K=256 -> 2 x 128)
    splitk_gemm<<<340, 256, 0, stream>>>(attn, woT, part, 128, 256, 256);
    // x = LN(part0 + part1 + b_out + src) -> xbuf (+ bf16 copy)
    add_ln2<<<MROWS, 256, 0, stream>>>(part, part + (size_t)MROWS * 256, b_out, src,
                                       g1, be1, xbuf, xb16);

    // ---- FFN ----
    // hb = relu(x @ w1 + b1)  (bf16 A, 1360 swizzled blocks)
    ffn1_gemm<<<1360, 256, 0, stream>>>(xb16, w1T, b1, hb, 2048, 256, 256, 256);
    // ffn2 split-K (K=2048 -> 2 x 1024)
    splitk_gemm<<<340, 256, 0, stream>>>(hb, w2T, part, 1024, 2048, 2048);
    // out = LN(part0 + part1 + b2 + xbuf)
    add_ln2<<<MROWS, 256, 0, stream>>>(part, part + (size_t)MROWS * 256, b2, xbuf,
                                       g2, be2, out, nullptr);
}

// Round 8
// 225.931 us; speedup vs baseline: 3.8841x; 1.0734x over previous
//
#include <hip/hip_runtime.h>
#include <math.h>

#define D 256
#define NH 8
#define NL 4
#define NP 4
#define DFF 2048
#define HD 32
#define BB 2
#define LEN 5440
#define MROWS (BB * LEN)   // 10880 = 85 * 128 exactly

typedef __attribute__((ext_vector_type(8))) short short8;
typedef __attribute__((ext_vector_type(4))) float f32x4;
typedef unsigned int uint32;

__device__ __forceinline__ unsigned short f2bf(float f) {
    uint32 u = __float_as_uint(f);
    u += 0x7FFF + ((u >> 16) & 1);           // round-to-nearest-even
    return (unsigned short)(u >> 16);
}
__device__ __forceinline__ float bf2f(unsigned short h) {
    return __uint_as_float(((uint32)h) << 16);
}
__device__ __forceinline__ uint32 pack2(float a, float b) {
    return (uint32)f2bf(a) | ((uint32)f2bf(b) << 16);
}

// XCD-affinity swizzle: 85 row-tiles x ncols col-tiles, flat block id ->
// (row, col) s.t. all cols of a row share id%8 (= XCD on round-robin HW).
__device__ __forceinline__ void swz85(int b, int ncols, int& row, int& col) {
    const int gsz = ncols << 3;      // 8 rows worth
    const int full = 10 * gsz;       // 80 rows in full groups
    if (b < full) {
        const int g = b / gsz, idx = b - g * gsz;
        row = (g << 3) + (idx & 7);
        col = idx >> 3;
    } else {                         // last 5 rows (affinity relaxed)
        const int idx = b - full;
        row = 80 + idx % 5;
        col = idx / 5;
    }
}

// ---------------------------------------------------------------------------
// prep: all weight transposes (fp32 [KxN] -> bf16 [NxK]) + bias concat.
// ---------------------------------------------------------------------------
__global__ void prep(const float* __restrict__ w_value, const float* __restrict__ w_off,
                     const float* __restrict__ w_attn, const float* __restrict__ w_out,
                     const float* __restrict__ w1, const float* __restrict__ w2,
                     const float* __restrict__ b_value, const float* __restrict__ b_off,
                     const float* __restrict__ b_attn,
                     unsigned short* __restrict__ wqvT, unsigned short* __restrict__ woT,
                     unsigned short* __restrict__ w1T, unsigned short* __restrict__ w2T,
                     float* __restrict__ bqv) {
    const int blk = blockIdx.x;
    if (blk >= 1248) {
        for (int i = threadIdx.x; i < 640; i += 256)
            bqv[i] = (i < 256) ? b_value[i] : (i < 512 ? b_off[i - 256] : b_attn[i - 512]);
        return;
    }
    const float* W; unsigned short* WT; int K, N, tid;
    if (blk < 64)       { W = w_value; WT = wqvT;             K = 256;  N = 256;  tid = blk; }
    else if (blk < 128) { W = w_off;   WT = wqvT + 256 * 256; K = 256;  N = 256;  tid = blk - 64; }
    else if (blk < 160) { W = w_attn;  WT = wqvT + 512 * 256; K = 256;  N = 128;  tid = blk - 128; }
    else if (blk < 224) { W = w_out;   WT = woT;              K = 256;  N = 256;  tid = blk - 160; }
    else if (blk < 736) { W = w1;      WT = w1T;              K = 256;  N = 2048; tid = blk - 224; }
    else                { W = w2;      WT = w2T;              K = 2048; N = 256;  tid = blk - 736; }
    const int ntx = N >> 5;
    const int nb = (tid % ntx) * 32, kb = (tid / ntx) * 32;

    __shared__ float tile[32][33];
    const int tx = threadIdx.x & 31, ty = threadIdx.x >> 5;
#pragma unroll
    for (int i = 0; i < 32; i += 8)
        tile[ty + i][tx] = W[(size_t)(kb + ty + i) * N + nb + tx];
    __syncthreads();
#pragma unroll
    for (int i = 0; i < 32; i += 8)
        WT[(size_t)(nb + ty + i) * K + kb + tx] = f2bf(tile[tx][ty + i]);
}

// ---------------------------------------------------------------------------
// ffn1 GEMM: C = relu(A @ BT^T + bias) -> bf16. A bf16. 128x128 tile.
// K-loop software-pipelined: tile k+1 prefetched into regs during k's MFMAs.
// ---------------------------------------------------------------------------
__global__ __launch_bounds__(256) void ffn1_gemm(
        const unsigned short* __restrict__ A,
        const unsigned short* __restrict__ BT, const float* __restrict__ bias,
        unsigned short* __restrict__ Cv, int N, int K, int lda, int ldb) {
    __shared__ unsigned short Ash[128][40];
    __shared__ unsigned short Bsh[128][40];

    int rowt, colt;
    swz85(blockIdx.x, N >> 7, rowt, colt);
    const int row0 = rowt * 128, col0 = colt * 128;

    const int t = threadIdx.x;
    const int wave = t >> 6, lane = t & 63;
    const int wr = wave >> 1, wc = wave & 1;
    const int lrow = lane & 15, quad = lane >> 4;
    const int srow = t >> 1;
    const int cb = (t & 1) * 16;

    const unsigned short* ap = A + (size_t)(row0 + srow) * lda + cb;
    const unsigned short* bp = BT + (size_t)(col0 + srow) * ldb + cb;

    f32x4 acc[4][4];
#pragma unroll
    for (int i = 0; i < 4; i++)
#pragma unroll
        for (int j = 0; j < 4; j++) acc[i][j] = (f32x4){0.f, 0.f, 0.f, 0.f};

    uint4 ra0 = *(const uint4*)(ap + 0), ra1 = *(const uint4*)(ap + 8);
    uint4 rb0 = *(const uint4*)(bp + 0), rb1 = *(const uint4*)(bp + 8);

    for (int kb = 0; kb < K; kb += 32) {
        __syncthreads();
        *(uint4*)&Ash[srow][cb + 0] = ra0;
        *(uint4*)&Ash[srow][cb + 8] = ra1;
        *(uint4*)&Bsh[srow][cb + 0] = rb0;
        *(uint4*)&Bsh[srow][cb + 8] = rb1;
        __syncthreads();
        if (kb + 32 < K) {
            ra0 = *(const uint4*)(ap + kb + 32 + 0);
            ra1 = *(const uint4*)(ap + kb + 32 + 8);
            rb0 = *(const uint4*)(bp + kb + 32 + 0);
            rb1 = *(const uint4*)(bp + kb + 32 + 8);
        }

        short8 af[4], bfr[4];
#pragma unroll
        for (int mt = 0; mt < 4; mt++)
            af[mt] = *(const short8*)&Ash[wr * 64 + mt * 16 + lrow][quad * 8];
#pragma unroll
        for (int nt = 0; nt < 4; nt++)
            bfr[nt] = *(const short8*)&Bsh[wc * 64 + nt * 16 + lrow][quad * 8];
#pragma unroll
        for (int mt = 0; mt < 4; mt++)
#pragma unroll
            for (int nt = 0; nt < 4; nt++)
                acc[mt][nt] = __builtin_amdgcn_mfma_f32_16x16x32_bf16(
                    af[mt], bfr[nt], acc[mt][nt], 0, 0, 0);
    }

#pragma unroll
    for (int nt = 0; nt < 4; nt++) {
        const int col = col0 + wc * 64 + nt * 16 + lrow;
        const float bv = bias[col];
#pragma unroll
        for (int mt = 0; mt < 4; mt++) {
            f32x4 a = acc[mt][nt];
#pragma unroll
            for (int r = 0; r < 4; r++) {
                const int row = row0 + wr * 64 + mt * 16 + quad * 4 + r;
                Cv[(size_t)row * N + col] = f2bf(fmaxf(a[r] + bv, 0.f));
            }
        }
    }
}

// ---------------------------------------------------------------------------
// Split-K GEMM (N=256): flat grid 85 x (2 cols x NZ kchunks), swizzled.
// partial[z] = A[:, z*KC:] @ BT[:, z*KC:]^T (fp32). Pipelined K-loop.
// ---------------------------------------------------------------------------
template <int NZ>
__global__ __launch_bounds__(256) void splitk_gemm(
        const unsigned short* __restrict__ A, const unsigned short* __restrict__ BT,
        float* __restrict__ part, int KC, int lda, int ldb) {
    __shared__ unsigned short Ash[128][40];
    __shared__ unsigned short Bsh[128][40];

    int rowt, cc;
    swz85(blockIdx.x, 2 * NZ, rowt, cc);
    const int row0 = rowt * 128;
    const int col0 = (cc & 1) * 128;
    const int z = cc >> 1;
    const int koff = z * KC;
    float* __restrict__ C = part + (size_t)z * MROWS * 256;

    const int t = threadIdx.x;
    const int wave = t >> 6, lane = t & 63;
    const int wr = wave >> 1, wc = wave & 1;
    const int lrow = lane & 15, quad = lane >> 4;
    const int srow = t >> 1;
    const int cb = (t & 1) * 16;

    const unsigned short* ap = A + (size_t)(row0 + srow) * lda + koff + cb;
    const unsigned short* bp = BT + (size_t)(col0 + srow) * ldb + koff + cb;

    f32x4 acc[4][4];
#pragma unroll
    for (int i = 0; i < 4; i++)
#pragma unroll
        for (int j = 0; j < 4; j++) acc[i][j] = (f32x4){0.f, 0.f, 0.f, 0.f};

    uint4 ra0 = *(const uint4*)(ap + 0), ra1 = *(const uint4*)(ap + 8);
    uint4 rb0 = *(const uint4*)(bp + 0), rb1 = *(const uint4*)(bp + 8);

    for (int kb = 0; kb < KC; kb += 32) {
        __syncthreads();
        *(uint4*)&Ash[srow][cb + 0] = ra0;
        *(uint4*)&Ash[srow][cb + 8] = ra1;
        *(uint4*)&Bsh[srow][cb + 0] = rb0;
        *(uint4*)&Bsh[srow][cb + 8] = rb1;
        __syncthreads();
        if (kb + 32 < KC) {
            ra0 = *(const uint4*)(ap + kb + 32 + 0);
            ra1 = *(const uint4*)(ap + kb + 32 + 8);
            rb0 = *(const uint4*)(bp + kb + 32 + 0);
            rb1 = *(const uint4*)(bp + kb + 32 + 8);
        }

        short8 af[4], bfr[4];
#pragma unroll
        for (int mt = 0; mt < 4; mt++)
            af[mt] = *(const short8*)&Ash[wr * 64 + mt * 16 + lrow][quad * 8];
#pragma unroll
        for (int nt = 0; nt < 4; nt++)
            bfr[nt] = *(const short8*)&Bsh[wc * 64 + nt * 16 + lrow][quad * 8];
#pragma unroll
        for (int mt = 0; mt < 4; mt++)
#pragma unroll
            for (int nt = 0; nt < 4; nt++)
                acc[mt][nt] = __builtin_amdgcn_mfma_f32_16x16x32_bf16(
                    af[mt], bfr[nt], acc[mt][nt], 0, 0, 0);
    }

#pragma unroll
    for (int nt = 0; nt < 4; nt++) {
        const int col = col0 + wc * 64 + nt * 16 + lrow;
#pragma unroll
        for (int mt = 0; mt < 4; mt++) {
            f32x4 a = acc[mt][nt];
#pragma unroll
            for (int r = 0; r < 4; r++) {
                const int row = row0 + wr * 64 + mt * 16 + quad * 4 + r;
                C[(size_t)row * 256 + col] = a[r];
            }
        }
    }
}

// ---------------------------------------------------------------------------
// Merged value+query GEMM: flat grid 425 = 85 rows x 5 cols, swizzled.
// col < 256 -> val (bf16); col >= 256 -> qout (fp32, stride 384). Pipelined.
// ---------------------------------------------------------------------------
__global__ __launch_bounds__(256) void qv_gemm(
        const float* __restrict__ src, const float* __restrict__ pos,
        const unsigned short* __restrict__ BT, const float* __restrict__ bias,
        unsigned short* __restrict__ val, float* __restrict__ qout) {
    __shared__ unsigned short Ash[128][40];
    __shared__ unsigned short Bsh[128][40];

    int rowt, colt;
    swz85(blockIdx.x, 5, rowt, colt);
    const int row0 = rowt * 128, col0 = colt * 128;
    const bool addp = (col0 >= 256);

    const int t = threadIdx.x;
    const int wave = t >> 6, lane = t & 63;
    const int wr = wave >> 1, wc = wave & 1;
    const int lrow = lane & 15, quad = lane >> 4;
    const int srow = t >> 1;
    const int cb = (t & 1) * 16;

    const float* ap = src + (size_t)(row0 + srow) * 256 + cb;
    const float* pp = pos + (size_t)(row0 + srow) * 256 + cb;
    const unsigned short* bp = BT + (size_t)(col0 + srow) * 256 + cb;

    f32x4 acc[4][4];
#pragma unroll
    for (int i = 0; i < 4; i++)
#pragma unroll
        for (int j = 0; j < 4; j++) acc[i][j] = (f32x4){0.f, 0.f, 0.f, 0.f};

    float4 fa[4]; float4 fp[4]; uint4 rb0, rb1;
#pragma unroll
    for (int j = 0; j < 4; j++) fa[j] = *(const float4*)(ap + 4 * j);
    if (addp) {
#pragma unroll
        for (int j = 0; j < 4; j++) fp[j] = *(const float4*)(pp + 4 * j);
    }
    rb0 = *(const uint4*)(bp + 0);
    rb1 = *(const uint4*)(bp + 8);

    for (int kb = 0; kb < 256; kb += 32) {
        __syncthreads();
        {
            float4 f0 = fa[0], f1 = fa[1], f2 = fa[2], f3 = fa[3];
            if (addp) {
                f0.x += fp[0].x; f0.y += fp[0].y; f0.z += fp[0].z; f0.w += fp[0].w;
                f1.x += fp[1].x; f1.y += fp[1].y; f1.z += fp[1].z; f1.w += fp[1].w;
                f2.x += fp[2].x; f2.y += fp[2].y; f2.z += fp[2].z; f2.w += fp[2].w;
                f3.x += fp[3].x; f3.y += fp[3].y; f3.z += fp[3].z; f3.w += fp[3].w;
            }
            uint4 u0 = make_uint4(pack2(f0.x, f0.y), pack2(f0.z, f0.w),
                                  pack2(f1.x, f1.y), pack2(f1.z, f1.w));
            uint4 u1 = make_uint4(pack2(f2.x, f2.y), pack2(f2.z, f2.w),
                                  pack2(f3.x, f3.y), pack2(f3.z, f3.w));
            *(uint4*)&Ash[srow][cb + 0] = u0;
            *(uint4*)&Ash[srow][cb + 8] = u1;
            *(uint4*)&Bsh[srow][cb + 0] = rb0;
            *(uint4*)&Bsh[srow][cb + 8] = rb1;
        }
        __syncthreads();
        if (kb + 32 < 256) {
#pragma unroll
            for (int j = 0; j < 4; j++) fa[j] = *(const float4*)(ap + kb + 32 + 4 * j);
            if (addp) {
#pragma unroll
                for (int j = 0; j < 4; j++) fp[j] = *(const float4*)(pp + kb + 32 + 4 * j);
            }
            rb0 = *(const uint4*)(bp + kb + 32 + 0);
            rb1 = *(const uint4*)(bp + kb + 32 + 8);
        }

        short8 af[4], bfr[4];
#pragma unroll
        for (int mt = 0; mt < 4; mt++)
            af[mt] = *(const short8*)&Ash[wr * 64 + mt * 16 + lrow][quad * 8];
#pragma unroll
        for (int nt = 0; nt < 4; nt++)
            bfr[nt] = *(const short8*)&Bsh[wc * 64 + nt * 16 + lrow][quad * 8];
#pragma unroll
        for (int mt = 0; mt < 4; mt++)
#pragma unroll
            for (int nt = 0; nt < 4; nt++)
                acc[mt][nt] = __builtin_amdgcn_mfma_f32_16x16x32_bf16(
                    af[mt], bfr[nt], acc[mt][nt], 0, 0, 0);
    }

#pragma unroll
    for (int nt = 0; nt < 4; nt++) {
        const int col = col0 + wc * 64 + nt * 16 + lrow;
        const float bv = bias[col];
#pragma unroll
        for (int mt = 0; mt < 4; mt++) {
            f32x4 a = acc[mt][nt];
#pragma unroll
            for (int r = 0; r < 4; r++) {
                const int row = row0 + wr * 64 + mt * 16 + quad * 4 + r;
                float v = a[r] + bv;
                if (col < 256)
                    val[(size_t)row * 256 + col] = f2bf(v);
                else
                    qout[(size_t)row * 384 + (col - 256)] = v;
            }
        }
    }
}

// ---------------------------------------------------------------------------
// Two-phase sampler (phase1: softmax+corner precompute -> LDS; phase2: gather)
// ---------------------------------------------------------------------------
__global__ void sampler(const unsigned short* __restrict__ val, const float* __restrict__ qout,
                        unsigned short* __restrict__ out) {
    __shared__ __align__(16) int   sIdx[128][4];
    __shared__ __align__(16) float sW[128][4];
    const int bq = blockIdx.x;
    const int b = bq / LEN, q = bq % LEN;
    const int t = threadIdx.x;

    if (t < 128) {
        const int h = t >> 4, p = t & 15;
        const int l = p >> 2;

        float refx, refy;
        if (q < 4096) {
            int rq = q >> 6, cq = q & 63;
            refx = (cq + 0.5f) * (1.0f / 64.0f);
            refy = (rq + 0.5f) * (1.0f / 64.0f);
        } else if (q < 5120) {
            int qq = q - 4096;
            int rq = qq >> 5, cq = qq & 31;
            refx = (cq + 0.5f) * (1.0f / 32.0f);
            refy = (rq + 0.5f) * (1.0f / 32.0f);
        } else if (q < 5376) {
            int qq = q - 5120;
            int rq = qq >> 4, cq = qq & 15;
            refx = (cq + 0.5f) * (1.0f / 16.0f);
            refy = (rq + 0.5f) * (1.0f / 16.0f);
        } else {
            int qq = q - 5376;
            int rq = qq >> 3, cq = qq & 7;
            refx = (cq + 0.5f) * (1.0f / 8.0f);
            refy = (rq + 0.5f) * (1.0f / 8.0f);
        }

        float lv = qout[(size_t)bq * 384 + 256 + t];
        float mx = lv;
#pragma unroll
        for (int o = 1; o < 16; o <<= 1) mx = fmaxf(mx, __shfl_xor(mx, o, 16));
        float e = expf(lv - mx);
        float s = e;
#pragma unroll
        for (int o = 1; o < 16; o <<= 1) s += __shfl_xor(s, o, 16);
        const float aw = e / s;

        const float ox = qout[(size_t)bq * 384 + h * 32 + p * 2 + 0];
        const float oy = qout[(size_t)bq * 384 + h * 32 + p * 2 + 1];

        const int LST[4] = {0, 4096, 5120, 5376};
        const int WW = 64 >> l;
        const float rw = 1.0f / (float)WW;

        float x = (refx + ox * rw) * (float)WW - 0.5f;
        float y = (refy + oy * rw) * (float)WW - 0.5f;
        float x0f = floorf(x), y0f = floorf(y);
        float dx = x - x0f, dy = y - y0f;
        int x0 = (int)x0f, y0 = (int)y0f;

        const int base = (b * LEN + LST[l]) * 256 + h * 32;
        int4 iv; float4 wv;
        {
            int xs[2] = {x0, x0 + 1}, ys[2] = {y0, y0 + 1};
            float wx[2] = {1.f - dx, dx}, wy[2] = {1.f - dy, dy};
            int ic[4]; float wc4[4];
#pragma unroll
            for (int cy = 0; cy < 2; cy++)
#pragma unroll
                for (int cx = 0; cx < 2; cx++) {
                    int xi = xs[cx], yi = ys[cy];
                    bool vld = (xi >= 0) && (xi < WW) && (yi >= 0) && (yi < WW);
                    int xc = min(max(xi, 0), WW - 1);
                    int yc = min(max(yi, 0), WW - 1);
                    ic[cy * 2 + cx] = base + (yc * WW + xc) * 256;
                    wc4[cy * 2 + cx] = vld ? wx[cx] * wy[cy] * aw : 0.f;
                }
            iv = make_int4(ic[0], ic[1], ic[2], ic[3]);
            wv = make_float4(wc4[0], wc4[1], wc4[2], wc4[3]);
        }
        *(int4*)&sIdx[t][0] = iv;
        *(float4*)&sW[t][0] = wv;
    }
    __syncthreads();

    const int h = t >> 5, d = t & 31;
    const unsigned short* vald = val + d;
    float acc = 0.f;
#pragma unroll 4
    for (int p = 0; p < 16; p++) {
        const int r = h * 16 + p;
        int4 iv = *(const int4*)&sIdx[r][0];
        float4 wv = *(const float4*)&sW[r][0];
        acc += bf2f(vald[iv.x]) * wv.x;
        acc += bf2f(vald[iv.y]) * wv.y;
        acc += bf2f(vald[iv.z]) * wv.z;
        acc += bf2f(vald[iv.w]) * wv.w;
    }
    out[(size_t)bq * D + h * HD + d] = f2bf(acc);
}

// ---------------------------------------------------------------------------
// out = LayerNorm(sum_z part[z] + bias + rsd) * g + be  (one row per block)
// Optionally also writes bf16 copy (out16) for downstream bf16 GEMM A.
// ---------------------------------------------------------------------------
template <int NPART>
__global__ void add_lnN(const float* __restrict__ part, const float* __restrict__ bias,
                        const float* __restrict__ rsd,
                        const float* __restrict__ g, const float* __restrict__ be,
                        float* __restrict__ out, unsigned short* __restrict__ out16) {
    __shared__ float r1[4], r2[4];
    const int row = blockIdx.x, t = threadIdx.x;
    const size_t i = (size_t)row * D + t;
    float v = bias[t] + rsd[i];
#pragma unroll
    for (int z = 0; z < NPART; z++) v += part[(size_t)z * MROWS * 256 + i];
    float s1 = v, s2 = v * v;
#pragma unroll
    for (int o = 32; o > 0; o >>= 1) {
        s1 += __shfl_down(s1, o, 64);
        s2 += __shfl_down(s2, o, 64);
    }
    if ((t & 63) == 0) { r1[t >> 6] = s1; r2[t >> 6] = s2; }
    __syncthreads();
    float su = r1[0] + r1[1] + r1[2] + r1[3];
    float sq = r2[0] + r2[1] + r2[2] + r2[3];
    float mean = su * (1.0f / D);
    float var = fmaxf(sq * (1.0f / D) - mean * mean, 0.f);
    const float o = (v - mean) * rsqrtf(var + 1e-5f) * g[t] + be[t];
    out[i] = o;
    if (out16) out16[i] = f2bf(o);
}

// ---------------------------------------------------------------------------
extern "C" void kernel_launch(void* const* d_in, const int* in_sizes, int n_in,
                              void* d_out, int out_size, void* d_ws, size_t ws_size,
                              hipStream_t stream) {
    const float* src     = (const float*)d_in[0];
    const float* pos     = (const float*)d_in[1];
    const float* w_value = (const float*)d_in[4];
    const float* b_value = (const float*)d_in[5];
    const float* w_off   = (const float*)d_in[6];
    const float* b_off   = (const float*)d_in[7];
    const float* w_attn  = (const float*)d_in[8];
    const float* b_attn  = (const float*)d_in[9];
    const float* w_out   = (const float*)d_in[10];
    const float* b_out   = (const float*)d_in[11];
    const float* w1      = (const float*)d_in[12];
    const float* b1      = (const float*)d_in[13];
    const float* w2      = (const float*)d_in[14];
    const float* b2      = (const float*)d_in[15];
    const float* g1      = (const float*)d_in[16];
    const float* be1     = (const float*)d_in[17];
    const float* g2      = (const float*)d_in[18];
    const float* be2     = (const float*)d_in[19];
    float* out = (float*)d_out;

    // ---- workspace layout (~136 MB of the 256 MiB ws) ----
    size_t off = 0;
    auto alloc = [&](size_t bytes) -> char* {
        char* p = (char*)d_ws + off;
        off += (bytes + 255) & ~(size_t)255;
        return p;
    };
    unsigned short* wqvT = (unsigned short*)alloc((size_t)640 * 256 * 2);
    unsigned short* woT  = (unsigned short*)alloc(256 * 256 * 2);
    unsigned short* w1T  = (unsigned short*)alloc((size_t)2048 * 256 * 2);
    unsigned short* w2T  = (unsigned short*)alloc((size_t)256 * 2048 * 2);
    float* bqv           = (float*)alloc(640 * 4);

    float* qout          = (float*)alloc((size_t)MROWS * 384 * 4);   // 16.71 MB
    unsigned short* val  = (unsigned short*)alloc((size_t)MROWS * 256 * 2);
    unsigned short* attn = (unsigned short*)alloc((size_t)MROWS * 256 * 2);
    unsigned short* hb   = (unsigned short*)alloc((size_t)MROWS * 2048 * 2);  // 44.6 MB
    float* xbuf          = (float*)alloc((size_t)MROWS * 256 * 4);
    unsigned short* xb16 = (unsigned short*)alloc((size_t)MROWS * 256 * 2);
    float* part          = (float*)alloc((size_t)4 * MROWS * 256 * 4);        // 44.6 MB

    // ---- weight prep (single launch) ----
    prep<<<1249, 256, 0, stream>>>(w_value, w_off, w_attn, w_out, w1, w2,
                                   b_value, b_off, b_attn, wqvT, woT, w1T, w2T, bqv);

    // ---- attention ----
    qv_gemm<<<425, 256, 0, stream>>>(src, pos, wqvT, bqv, val, qout);
    sampler<<<MROWS, 256, 0, stream>>>(val, qout, attn);
    // proj split-K (K=256 -> 2 x 128)
    splitk_gemm<2><<<340, 256, 0, stream>>>(attn, woT, part, 128, 256, 256);
    // x = LN(part0 + part1 + b_out + src) -> xbuf (+ bf16 copy)
    add_lnN<2><<<MROWS, 256, 0, stream>>>(part, b_out, src, g1, be1, xbuf, xb16);

    // ---- FFN ----
    // hb = relu(x @ w1 + b1)  (bf16 A, 1360 swizzled blocks, pipelined)
    ffn1_gemm<<<1360, 256, 0, stream>>>(xb16, w1T, b1, hb, 2048, 256, 256, 256);
    // ffn2 split-K (K=2048 -> 4 x 512, 680 blocks)
    splitk_gemm<4><<<680, 256, 0, stream>>>(hb, w2T, part, 512, 2048, 2048);
    // out = LN(part0..3 + b2 + xbuf)
    add_lnN<4><<<MROWS, 256, 0, stream>>>(part, b2, xbuf, g2, be2, out, nullptr);
}